// Round 9
// baseline (310.879 us; speedup 1.0000x reference)
//
#include <hip/hip_runtime.h>
#include <hip/hip_bf16.h>

typedef unsigned int u32;
typedef unsigned short u16;
typedef short bf16x8 __attribute__((ext_vector_type(8)));
typedef float f32x4 __attribute__((ext_vector_type(4)));

static __device__ __forceinline__ float bf_lo(u32 v) { return __uint_as_float(v << 16); }
static __device__ __forceinline__ float bf_hi(u32 v) { return __uint_as_float(v & 0xffff0000u); }
static __device__ __forceinline__ u16 f2bf(float f) {
    u32 u = __float_as_uint(f);
    u32 r = u + 0x7fffu + ((u >> 16) & 1u);   // RNE; inputs finite
    return (u16)(r >> 16);
}
static __device__ __forceinline__ u32 pack2(float a, float b) {
    return ((u32)f2bf(b) << 16) | (u32)f2bf(a);
}

// ---------------------------------------------------------------------------
// f32 -> bf16 convert (row-major, packed pairs)
// ---------------------------------------------------------------------------
__global__ __launch_bounds__(256) void convert_k(const float* __restrict__ in,
                                                 u32* __restrict__ out2, int total4)
{
    for (int i = blockIdx.x * 256 + threadIdx.x; i < total4; i += gridDim.x * 256) {
        float4 v = reinterpret_cast<const float4*>(in)[i];
        out2[2 * i + 0] = pack2(v.x, v.y);
        out2[2 * i + 1] = pack2(v.z, v.w);
    }
}

// ---------------------------------------------------------------------------
// weight prep (all 4 mats in one launch): W (128x128 f32, row-major W[k][n])
// -> fragment-ordered bf16
// Wf[((kg*8+nb)*64 + l)*8 + j] = W[kg*32 + (l>>4)*8 + j][nb*16 + (l&15)]
// ---------------------------------------------------------------------------
__global__ __launch_bounds__(256) void wprep_k(const float* __restrict__ Wa,
                                               const float* __restrict__ Wb,
                                               const float* __restrict__ Wc,
                                               const float* __restrict__ Wd,
                                               u16* __restrict__ Wf)
{
    int g = blockIdx.x * 256 + threadIdx.x;   // 0..65535
    int which = g >> 14;
    int t = g & 16383;
    const float* W = which == 0 ? Wa : which == 1 ? Wb : which == 2 ? Wc : Wd;
    int j  = t & 7;
    int l  = (t >> 3) & 63;
    int nb = (t >> 9) & 7;
    int kg = (t >> 12) & 3;
    int k  = kg * 32 + (l >> 4) * 8 + j;
    int n  = nb * 16 + (l & 15);
    Wf[g] = f2bf(W[k * 128 + n]);
}

// ---------------------------------------------------------------------------
// Coarse bucket sort by dst>>7 (128 rows/bucket). NB <= 1024, N <= 131072.
// packed edge: (dst&127)<<17 | src   (src needs 17 bits)
// ---------------------------------------------------------------------------
__global__ __launch_bounds__(256) void bhist_k(const int* __restrict__ edst,
                                               int* __restrict__ gcount, int E, int NB)
{
    __shared__ int lh[1024];
    for (int i = threadIdx.x; i < 1024; i += 256) lh[i] = 0;
    __syncthreads();
    for (int e = blockIdx.x * 256 + threadIdx.x; e < E; e += gridDim.x * 256)
        atomicAdd(&lh[edst[e] >> 7], 1);
    __syncthreads();
    for (int b = threadIdx.x; b < NB; b += 256)
        if (lh[b]) atomicAdd(&gcount[b], lh[b]);
}

__global__ __launch_bounds__(1024) void bscan_k(const int* __restrict__ gcount,
                                                int* __restrict__ goffs,
                                                int* __restrict__ gcur, int NB)
{
    __shared__ int s[1024];
    int t = threadIdx.x;
    int v = (t < NB) ? gcount[t] : 0;
    s[t] = v; __syncthreads();
    for (int d = 1; d < 1024; d <<= 1) {
        int x = (t >= d) ? s[t - d] : 0;
        __syncthreads();
        s[t] += x;
        __syncthreads();
    }
    if (t < NB) { int o = s[t] - v; goffs[t] = o; gcur[t] = o; }
    if (t == NB - 1) goffs[NB] = s[t];
}

__global__ __launch_bounds__(256) void bfill_k(const int* __restrict__ esrc,
                                               const int* __restrict__ edst,
                                               int* __restrict__ gcur,
                                               u32* __restrict__ bpacked, int E, int NB)
{
    __shared__ int lh[1024];
    __shared__ int lbase[1024];
    int t = threadIdx.x;
    for (int i = t; i < 1024; i += 256) lh[i] = 0;
    __syncthreads();
    int per = (E + gridDim.x - 1) / gridDim.x;
    int lo = blockIdx.x * per;
    int hi = lo + per; if (hi > E) hi = E;
    for (int e = lo + t; e < hi; e += 256) atomicAdd(&lh[edst[e] >> 7], 1);
    __syncthreads();
    for (int b = t; b < NB; b += 256) {
        int c = lh[b];
        lbase[b] = c ? atomicAdd(&gcur[b], c) : 0;
    }
    __syncthreads();
    for (int i = t; i < 1024; i += 256) lh[i] = 0;   // reuse as local cursor
    __syncthreads();
    for (int e = lo + t; e < hi; e += 256) {
        int d = edst[e];
        int b = d >> 7;
        int idx = atomicAdd(&lh[b], 1);
        bpacked[lbase[b] + idx] = ((u32)(d & 127) << 17) | (u32)esrc[e];
    }
}

// ---------------------------------------------------------------------------
// fine counting sort within each bucket -> dst-sorted slots + per-row offs/deg
// ---------------------------------------------------------------------------
__global__ __launch_bounds__(256) void fsort_k(const u32* __restrict__ bpacked,
                                               const int* __restrict__ goffs,
                                               int* __restrict__ slots,
                                               int* __restrict__ offs,
                                               int* __restrict__ deg, int N)
{
    __shared__ int cnt[128];
    __shared__ int roff[128];
    int b = blockIdx.x, t = threadIdx.x;
    int start = goffs[b], end = goffs[b + 1];
    if (t < 128) cnt[t] = 0;
    __syncthreads();
    for (int e = start + t; e < end; e += 256)
        atomicAdd(&cnt[bpacked[e] >> 17], 1);
    __syncthreads();
    if (t == 0) {
        int acc = 0;
        for (int i = 0; i < 128; ++i) { roff[i] = acc; acc += cnt[i]; }
    }
    __syncthreads();
    int row0 = b * 128;
    if (t < 128 && row0 + t < N) {
        offs[row0 + t] = start + roff[t];
        deg[row0 + t]  = cnt[t];
    }
    if (t < 128) cnt[t] = 0;   // reuse as cursor
    __syncthreads();
    for (int e = start + t; e < end; e += 256) {
        u32 pk = bpacked[e];
        int local = (int)(pk >> 17);
        int idx = atomicAdd(&cnt[local], 1);
        slots[start + roff[local] + idx] = (int)(pk & 0x1FFFF);
    }
}

// ---------------------------------------------------------------------------
// gather-aggregate, DUAL-ROW: each wave processes 2 rows concurrently so the
// two per-row latency chains (slot load -> shfl -> 8 row loads) overlap ->
// ~16 loads in flight per wave (round 8: 8 in flight, latency-bound 68us).
// MODE 0: xa[row] = bf16( x[row] + sum_nbr x[s] )
// MODE 1: prev-layer BN folded in: xa[row] = bf16( sc.(h+sum) + (deg+1).sh )
// ---------------------------------------------------------------------------
template<int MODE>
__global__ __launch_bounds__(256) void gather_k(const u32* __restrict__ xb2,
                                                const int* __restrict__ offs,
                                                const int* __restrict__ deg,
                                                const int* __restrict__ slots,
                                                const float* __restrict__ stats_in,
                                                const float* __restrict__ g_in,
                                                const float* __restrict__ be_in,
                                                u32* __restrict__ xa2, int N)
{
    __shared__ float sc[128], sh[128];
    int t = threadIdx.x;
    if (MODE == 1) {
        if (t < 128) {
            float invN = 1.0f / (float)N;
            float mean = stats_in[t] * invN;
            float var  = stats_in[128 + t] * invN - mean * mean;
            float s = g_in[t] * rsqrtf(var + 1e-5f);
            sc[t] = s;
            sh[t] = be_in[t] - mean * s;
        }
        __syncthreads();
    }

    int lane = t & 63;
    int rowA = blockIdx.x * 8 + (t >> 6) * 2;
    int rowB = rowA + 1;
    bool okA = rowA < N, okB = rowB < N;
    if (!okA) return;

    u32 selfA = xb2[(size_t)rowA * 64 + lane];
    u32 selfB = okB ? xb2[(size_t)rowB * 64 + lane] : 0;
    float axA0 = bf_lo(selfA), ayA0 = bf_hi(selfA), axA1 = 0.f, ayA1 = 0.f;
    float axB0 = bf_lo(selfB), ayB0 = bf_hi(selfB), axB1 = 0.f, ayB1 = 0.f;

    int startA = offs[rowA];
    int dgA = deg[rowA];
    int startB = okB ? offs[rowB] : 0;
    int dgB = okB ? deg[rowB] : 0;
    int dgMax = dgA > dgB ? dgA : dgB;

    for (int base = 0; base < dgMax; base += 64) {
        int remA = dgA - base; int mA = remA < 0 ? 0 : (remA > 64 ? 64 : remA);
        int remB = dgB - base; int mB = remB < 0 ? 0 : (remB > 64 ? 64 : remB);
        int slotA = (lane < mA) ? slots[startA + base + lane] : 0;
        int slotB = (lane < mB) ? slots[startB + base + lane] : 0;
        int mMin = mA < mB ? mA : mB;
        int mMax = mA > mB ? mA : mB;
        int j = 0;
        // joint full groups: both rows unmasked, 16 loads in flight
        for (; j + 8 <= mMin; j += 8) {
            int a0 = __shfl(slotA, j + 0), b0 = __shfl(slotB, j + 0);
            int a1 = __shfl(slotA, j + 1), b1 = __shfl(slotB, j + 1);
            int a2 = __shfl(slotA, j + 2), b2 = __shfl(slotB, j + 2);
            int a3 = __shfl(slotA, j + 3), b3 = __shfl(slotB, j + 3);
            int a4 = __shfl(slotA, j + 4), b4 = __shfl(slotB, j + 4);
            int a5 = __shfl(slotA, j + 5), b5 = __shfl(slotB, j + 5);
            int a6 = __shfl(slotA, j + 6), b6 = __shfl(slotB, j + 6);
            int a7 = __shfl(slotA, j + 7), b7 = __shfl(slotB, j + 7);
            u32 vA0 = xb2[(size_t)a0 * 64 + lane], vB0 = xb2[(size_t)b0 * 64 + lane];
            u32 vA1 = xb2[(size_t)a1 * 64 + lane], vB1 = xb2[(size_t)b1 * 64 + lane];
            u32 vA2 = xb2[(size_t)a2 * 64 + lane], vB2 = xb2[(size_t)b2 * 64 + lane];
            u32 vA3 = xb2[(size_t)a3 * 64 + lane], vB3 = xb2[(size_t)b3 * 64 + lane];
            u32 vA4 = xb2[(size_t)a4 * 64 + lane], vB4 = xb2[(size_t)b4 * 64 + lane];
            u32 vA5 = xb2[(size_t)a5 * 64 + lane], vB5 = xb2[(size_t)b5 * 64 + lane];
            u32 vA6 = xb2[(size_t)a6 * 64 + lane], vB6 = xb2[(size_t)b6 * 64 + lane];
            u32 vA7 = xb2[(size_t)a7 * 64 + lane], vB7 = xb2[(size_t)b7 * 64 + lane];
            axA0 += bf_lo(vA0); ayA0 += bf_hi(vA0); axB0 += bf_lo(vB0); ayB0 += bf_hi(vB0);
            axA1 += bf_lo(vA1); ayA1 += bf_hi(vA1); axB1 += bf_lo(vB1); ayB1 += bf_hi(vB1);
            axA0 += bf_lo(vA2); ayA0 += bf_hi(vA2); axB0 += bf_lo(vB2); ayB0 += bf_hi(vB2);
            axA1 += bf_lo(vA3); ayA1 += bf_hi(vA3); axB1 += bf_lo(vB3); ayB1 += bf_hi(vB3);
            axA0 += bf_lo(vA4); ayA0 += bf_hi(vA4); axB0 += bf_lo(vB4); ayB0 += bf_hi(vB4);
            axA1 += bf_lo(vA5); ayA1 += bf_hi(vA5); axB1 += bf_lo(vB5); ayB1 += bf_hi(vB5);
            axA0 += bf_lo(vA6); ayA0 += bf_hi(vA6); axB0 += bf_lo(vB6); ayB0 += bf_hi(vB6);
            axA1 += bf_lo(vA7); ayA1 += bf_hi(vA7); axB1 += bf_lo(vB7); ayB1 += bf_hi(vB7);
        }
        // ragged remainder: masked adds (safe slot 0 -> L2-hot row 0)
        for (; j < mMax; ++j) {
            int a = __shfl(slotA, j);
            int b = __shfl(slotB, j);
            u32 vA = xb2[(size_t)a * 64 + lane];
            u32 vB = xb2[(size_t)b * 64 + lane];
            if (j < mA) { axA0 += bf_lo(vA); ayA0 += bf_hi(vA); }
            if (j < mB) { axB0 += bf_lo(vB); ayB0 += bf_hi(vB); }
        }
    }

    float axA = axA0 + axA1, ayA = ayA0 + ayA1;
    float axB = axB0 + axB1, ayB = ayB0 + ayB1;
    if (MODE == 1) {
        float scl = sc[2 * lane], sch = sc[2 * lane + 1];
        float shl = sh[2 * lane], shh = sh[2 * lane + 1];
        float d1A = (float)(dgA + 1);
        float d1B = (float)(dgB + 1);
        axA = scl * axA + d1A * shl;  ayA = sch * ayA + d1A * shh;
        axB = scl * axB + d1B * shl;  ayB = sch * ayB + d1B * shh;
    }
    xa2[(size_t)rowA * 64 + lane] = pack2(axA, ayA);
    if (okB) xa2[(size_t)rowB * 64 + lane] = pack2(axB, ayB);
}

// ---------------------------------------------------------------------------
// fused MFMA MLP: h = relu(relu(XA@Wa + ba)@Wb + bb).
// BN stats -> per-block partial (coalesced store; no contended atomics).
// MODE 0: store bf16 h1.  MODE 1: store f32 h2.
// ---------------------------------------------------------------------------
template<int MODE>
__global__ __launch_bounds__(256) void mlp_mfma_k(
    const u16* __restrict__ xa,
    const u16* __restrict__ wfa, const float* __restrict__ ba,
    const u16* __restrict__ wfb, const float* __restrict__ bb,
    u16* __restrict__ hb_out, float* __restrict__ hf_out,
    float* __restrict__ partial, int N)
{
    __shared__ short ta[64 * 128];   // 16 KB tile (bf16, swizzled), reused
    __shared__ float ssum[256];

    int t = threadIdx.x;
    int w = t >> 6, l = t & 63;
    int row0 = blockIdx.x * 64;

    // stage XA tile (swizzled)
    for (int c = t; c < 1024; c += 256) {
        int r = c >> 4, ci = c & 15;
        int dst = (r * 128 + ci * 8) ^ ((r & 7) << 3);
        f32x4 v;
        if (row0 + r < N)
            v = *reinterpret_cast<const f32x4*>(xa + ((size_t)(row0 + r) * 128 + ci * 8));
        else
            v = f32x4{0.f, 0.f, 0.f, 0.f};
        *reinterpret_cast<f32x4*>(ta + dst) = v;
    }

    // W1 fragments for this wave's two 16-col blocks
    bf16x8 wf[2][4];
#pragma unroll
    for (int nr = 0; nr < 2; ++nr) {
        int nb = 2 * w + nr;
#pragma unroll
        for (int kg = 0; kg < 4; ++kg)
            wf[nr][kg] = *reinterpret_cast<const bf16x8*>(
                wfa + ((size_t)((kg * 8 + nb) * 64 + l)) * 8);
    }
    __syncthreads();

    int rr = l & 15;       // row within 16-tile
    int kg8 = l >> 4;      // k sub-group

    f32x4 acc[4][2];
#pragma unroll
    for (int mr = 0; mr < 4; ++mr)
#pragma unroll
        for (int nr = 0; nr < 2; ++nr)
            acc[mr][nr] = f32x4{0.f, 0.f, 0.f, 0.f};

#pragma unroll
    for (int mr = 0; mr < 4; ++mr) {
        int r = mr * 16 + rr;
        bf16x8 af[4];
#pragma unroll
        for (int kg = 0; kg < 4; ++kg) {
            int idx = (r * 128 + kg * 32 + kg8 * 8) ^ ((r & 7) << 3);
            af[kg] = *reinterpret_cast<const bf16x8*>(ta + idx);
        }
#pragma unroll
        for (int nr = 0; nr < 2; ++nr)
#pragma unroll
            for (int kg = 0; kg < 4; ++kg)
                acc[mr][nr] = __builtin_amdgcn_mfma_f32_16x16x32_bf16(
                    af[kg], wf[nr][kg], acc[mr][nr], 0, 0, 0);
    }
    __syncthreads();   // all GEMM1 reads of ta complete

    // bias + relu -> back into ta (bf16, swizzled)
    int colb = w * 32;
    float b0 = ba[colb + rr];
    float b1 = ba[colb + 16 + rr];
#pragma unroll
    for (int mr = 0; mr < 4; ++mr)
#pragma unroll
        for (int nr = 0; nr < 2; ++nr) {
            float bb_ = nr ? b1 : b0;
            int col = colb + nr * 16 + rr;
#pragma unroll
            for (int reg = 0; reg < 4; ++reg) {
                int row = mr * 16 + kg8 * 4 + reg;
                float v = fmaxf(acc[mr][nr][reg] + bb_, 0.0f);
                ta[(row * 128 + col) ^ ((row & 7) << 3)] = (short)f2bf(v);
            }
        }

    // W2 fragments
#pragma unroll
    for (int nr = 0; nr < 2; ++nr) {
        int nb = 2 * w + nr;
#pragma unroll
        for (int kg = 0; kg < 4; ++kg)
            wf[nr][kg] = *reinterpret_cast<const bf16x8*>(
                wfb + ((size_t)((kg * 8 + nb) * 64 + l)) * 8);
    }
    __syncthreads();   // intermediate tile fully written

#pragma unroll
    for (int mr = 0; mr < 4; ++mr)
#pragma unroll
        for (int nr = 0; nr < 2; ++nr)
            acc[mr][nr] = f32x4{0.f, 0.f, 0.f, 0.f};

#pragma unroll
    for (int mr = 0; mr < 4; ++mr) {
        int r = mr * 16 + rr;
        bf16x8 af[4];
#pragma unroll
        for (int kg = 0; kg < 4; ++kg) {
            int idx = (r * 128 + kg * 32 + kg8 * 8) ^ ((r & 7) << 3);
            af[kg] = *reinterpret_cast<const bf16x8*>(ta + idx);
        }
#pragma unroll
        for (int nr = 0; nr < 2; ++nr)
#pragma unroll
            for (int kg = 0; kg < 4; ++kg)
                acc[mr][nr] = __builtin_amdgcn_mfma_f32_16x16x32_bf16(
                    af[kg], wf[nr][kg], acc[mr][nr], 0, 0, 0);
    }

    // bias + relu + store + per-block BN stat partial
    float c0 = bb[colb + rr];
    float c1 = bb[colb + 16 + rr];
    float s0 = 0.f, q0 = 0.f, s1 = 0.f, q1 = 0.f;
#pragma unroll
    for (int mr = 0; mr < 4; ++mr) {
#pragma unroll
        for (int reg = 0; reg < 4; ++reg) {
            int row = row0 + mr * 16 + kg8 * 4 + reg;
            bool ok = row < N;
            float v0 = fmaxf(acc[mr][0][reg] + c0, 0.0f);
            float v1 = fmaxf(acc[mr][1][reg] + c1, 0.0f);
            if (ok) {
                if (MODE == 0) {
                    hb_out[(size_t)row * 128 + colb + rr]      = f2bf(v0);
                    hb_out[(size_t)row * 128 + colb + 16 + rr] = f2bf(v1);
                } else {
                    hf_out[(size_t)row * 128 + colb + rr]      = v0;
                    hf_out[(size_t)row * 128 + colb + 16 + rr] = v1;
                }
                s0 += v0; q0 += v0 * v0;
                s1 += v1; q1 += v1 * v1;
            }
        }
    }
    s0 += __shfl_xor(s0, 16); s0 += __shfl_xor(s0, 32);
    q0 += __shfl_xor(q0, 16); q0 += __shfl_xor(q0, 32);
    s1 += __shfl_xor(s1, 16); s1 += __shfl_xor(s1, 32);
    q1 += __shfl_xor(q1, 16); q1 += __shfl_xor(q1, 32);
    if (kg8 == 0) {            // each column owned by exactly one lane
        ssum[colb + rr]            = s0;
        ssum[128 + colb + rr]      = q0;
        ssum[colb + 16 + rr]       = s1;
        ssum[128 + colb + 16 + rr] = q1;
    }
    __syncthreads();
    partial[(size_t)blockIdx.x * 256 + t] = ssum[t];   // coalesced, no atomics
}

// ---------------------------------------------------------------------------
// reduce partials (nrows x 256) -> stats[256]; 32 blocks, 32 atomics/address
// ---------------------------------------------------------------------------
__global__ __launch_bounds__(256) void reduce_k(const float* __restrict__ partial,
                                                float* __restrict__ stats, int nrows)
{
    int t = threadIdx.x;
    int chunk = (nrows + gridDim.x - 1) / gridDim.x;
    int lo = blockIdx.x * chunk;
    int hi = lo + chunk; if (hi > nrows) hi = nrows;
    float acc = 0.f;
    for (int r = lo; r < hi; ++r)
        acc += partial[(size_t)r * 256 + t];
    if (hi > lo) atomicAdd(&stats[t], acc);
}

// ---------------------------------------------------------------------------
// final BN: in-place f32 on d_out
// ---------------------------------------------------------------------------
__global__ __launch_bounds__(256) void bn_apply_k(
    float* __restrict__ h, const float* __restrict__ stats,
    const float* __restrict__ gamma, const float* __restrict__ beta, int N)
{
    __shared__ float sc[128], sh[128];
    int t = threadIdx.x;
    if (t < 128) {
        float invN = 1.0f / (float)N;
        float mean = stats[t] * invN;
        float var  = stats[128 + t] * invN - mean * mean;
        float s = gamma[t] * rsqrtf(var + 1e-5f);
        sc[t] = s;
        sh[t] = beta[t] - mean * s;
    }
    __syncthreads();
    int total = N * 32;
    for (int i = blockIdx.x * 256 + t; i < total; i += gridDim.x * 256) {
        float4 v = reinterpret_cast<float4*>(h)[i];
        int c = (i & 31) * 4;
        v.x = v.x * sc[c + 0] + sh[c + 0];
        v.y = v.y * sc[c + 1] + sh[c + 1];
        v.z = v.z * sc[c + 2] + sh[c + 2];
        v.w = v.w * sc[c + 3] + sh[c + 3];
        reinterpret_cast<float4*>(h)[i] = v;
    }
}

// ---------------------------------------------------------------------------
extern "C" void kernel_launch(void* const* d_in, const int* in_sizes, int n_in,
                              void* d_out, int out_size, void* d_ws, size_t ws_size,
                              hipStream_t stream)
{
    const float* x   = (const float*)d_in[0];
    const int*   ei  = (const int*)d_in[1];
    const float* W1a = (const float*)d_in[2];
    const float* b1a = (const float*)d_in[3];
    const float* W1b = (const float*)d_in[4];
    const float* b1b = (const float*)d_in[5];
    const float* g1  = (const float*)d_in[6];
    const float* be1 = (const float*)d_in[7];
    const float* W2a = (const float*)d_in[8];
    const float* b2a = (const float*)d_in[9];
    const float* W2b = (const float*)d_in[10];
    const float* b2b = (const float*)d_in[11];
    const float* g2  = (const float*)d_in[12];
    const float* be2 = (const float*)d_in[13];

    const int N = in_sizes[0] / 128;
    const int E = in_sizes[1] / 2;
    const int* esrc = ei;
    const int* edst = ei + E;
    const int NB = (N + 127) >> 7;   // 128-row buckets; requires N <= 131072

    const int mblocks = (N + 63) / 64;
    const int gblocks = (N + 7) / 8;   // dual-row: 8 rows per block

    // ---- workspace carve ----
    char* p = (char*)d_ws;
    const size_t featb = (size_t)N * 128 * sizeof(u16);     // 25.6 MB
    u16* xa = (u16*)p;            p += featb;               // gather output
    u16* h1 = (u16*)p;            p += featb;               // layer-1 bf16 output
    u16* xb = (u16*)p;            p += featb;               // bf16 input features
    u16* wf = (u16*)p;            p += 4 * 16384 * sizeof(u16);
    int* slots = (int*)p;         p += (size_t)E * sizeof(int);
    int* deg   = (int*)p;         p += (size_t)N * sizeof(int);
    int* offs  = (int*)p;         p += (size_t)N * sizeof(int);
    int* gcount = (int*)p;        p += 1024 * sizeof(int);
    int* goffs  = (int*)p;        p += 1032 * sizeof(int);
    int* gcur   = (int*)p;        p += 1024 * sizeof(int);
    float* stats = (float*)p;     p += 512 * sizeof(float);
    float* partial = (float*)p;   p += (size_t)mblocks * 256 * sizeof(float);
    u32* bpacked = (u32*)xa;      // alias (E*4 = 6.4MB <= featb), dead early

    u16* wf1a = wf;
    u16* wf1b = wf + 16384;
    u16* wf2a = wf + 32768;
    u16* wf2b = wf + 49152;
    float* stats1 = stats;
    float* stats2 = stats + 256;

    float* h = (float*)d_out;

    // ---- one-time prep: bucket sort -> fine sort -> CSR; bf16 conversions ----
    hipMemsetAsync(gcount, 0, 1024 * sizeof(int), stream);
    bhist_k<<<256, 256, 0, stream>>>(edst, gcount, E, NB);
    bscan_k<<<1, 1024, 0, stream>>>(gcount, goffs, gcur, NB);
    bfill_k<<<256, 256, 0, stream>>>(esrc, edst, gcur, bpacked, E, NB);
    fsort_k<<<NB, 256, 0, stream>>>(bpacked, goffs, slots, offs, deg, N);
    convert_k<<<2048, 256, 0, stream>>>(x, (u32*)xb, N * 32);
    wprep_k<<<256, 256, 0, stream>>>(W1a, W1b, W2a, W2b, wf);
    hipMemsetAsync(stats, 0, 512 * sizeof(float), stream);

    // ---- layer 1: gather -> MLP (bf16 h1 + partial) -> reduce stats1 ----
    gather_k<0><<<gblocks, 256, 0, stream>>>((const u32*)xb, offs, deg, slots,
                                             nullptr, nullptr, nullptr, (u32*)xa, N);
    mlp_mfma_k<0><<<mblocks, 256, 0, stream>>>(xa, wf1a, b1a, wf1b, b1b,
                                               h1, (float*)nullptr, partial, N);
    reduce_k<<<32, 256, 0, stream>>>(partial, stats1, mblocks);

    // ---- layer 2: gather (BN1 folded) -> MLP (f32 h + partial) -> stats2 ----
    gather_k<1><<<gblocks, 256, 0, stream>>>((const u32*)h1, offs, deg, slots,
                                             stats1, g1, be1, (u32*)xa, N);
    mlp_mfma_k<1><<<mblocks, 256, 0, stream>>>(xa, wf2a, b2a, wf2b, b2b,
                                               (u16*)nullptr, h, partial, N);
    reduce_k<<<32, 256, 0, stream>>>(partial, stats2, mblocks);

    // ---- final BN in place on d_out ----
    bn_apply_k<<<2048, 256, 0, stream>>>(h, stats2, g2, be2, N);
}

// Round 10
// 298.297 us; speedup vs baseline: 1.0422x; 1.0422x over previous
//
#include <hip/hip_runtime.h>
#include <hip/hip_bf16.h>

typedef unsigned int u32;
typedef unsigned short u16;
typedef short bf16x8 __attribute__((ext_vector_type(8)));
typedef float f32x4 __attribute__((ext_vector_type(4)));

static __device__ __forceinline__ float bf_lo(u32 v) { return __uint_as_float(v << 16); }
static __device__ __forceinline__ float bf_hi(u32 v) { return __uint_as_float(v & 0xffff0000u); }
static __device__ __forceinline__ u16 f2bf(float f) {
    u32 u = __float_as_uint(f);
    u32 r = u + 0x7fffu + ((u >> 16) & 1u);   // RNE; inputs finite
    return (u16)(r >> 16);
}
static __device__ __forceinline__ u32 pack2(float a, float b) {
    return ((u32)f2bf(b) << 16) | (u32)f2bf(a);
}

// ---------------------------------------------------------------------------
// f32 -> bf16 convert (row-major, packed pairs)
// ---------------------------------------------------------------------------
__global__ __launch_bounds__(256) void convert_k(const float* __restrict__ in,
                                                 u32* __restrict__ out2, int total4)
{
    for (int i = blockIdx.x * 256 + threadIdx.x; i < total4; i += gridDim.x * 256) {
        float4 v = reinterpret_cast<const float4*>(in)[i];
        out2[2 * i + 0] = pack2(v.x, v.y);
        out2[2 * i + 1] = pack2(v.z, v.w);
    }
}

// ---------------------------------------------------------------------------
// weight prep (all 4 mats in one launch): W (128x128 f32, row-major W[k][n])
// -> fragment-ordered bf16
// Wf[((kg*8+nb)*64 + l)*8 + j] = W[kg*32 + (l>>4)*8 + j][nb*16 + (l&15)]
// ---------------------------------------------------------------------------
__global__ __launch_bounds__(256) void wprep_k(const float* __restrict__ Wa,
                                               const float* __restrict__ Wb,
                                               const float* __restrict__ Wc,
                                               const float* __restrict__ Wd,
                                               u16* __restrict__ Wf)
{
    int g = blockIdx.x * 256 + threadIdx.x;   // 0..65535
    int which = g >> 14;
    int t = g & 16383;
    const float* W = which == 0 ? Wa : which == 1 ? Wb : which == 2 ? Wc : Wd;
    int j  = t & 7;
    int l  = (t >> 3) & 63;
    int nb = (t >> 9) & 7;
    int kg = (t >> 12) & 3;
    int k  = kg * 32 + (l >> 4) * 8 + j;
    int n  = nb * 16 + (l & 15);
    Wf[g] = f2bf(W[k * 128 + n]);
}

// ---------------------------------------------------------------------------
// Coarse bucket sort by dst>>7 (128 rows/bucket). NB <= 1024, N <= 131072.
// packed edge: (dst&127)<<17 | src   (src needs 17 bits)
// ---------------------------------------------------------------------------
__global__ __launch_bounds__(256) void bhist_k(const int* __restrict__ edst,
                                               int* __restrict__ gcount, int E, int NB)
{
    __shared__ int lh[1024];
    for (int i = threadIdx.x; i < 1024; i += 256) lh[i] = 0;
    __syncthreads();
    for (int e = blockIdx.x * 256 + threadIdx.x; e < E; e += gridDim.x * 256)
        atomicAdd(&lh[edst[e] >> 7], 1);
    __syncthreads();
    for (int b = threadIdx.x; b < NB; b += 256)
        if (lh[b]) atomicAdd(&gcount[b], lh[b]);
}

__global__ __launch_bounds__(1024) void bscan_k(const int* __restrict__ gcount,
                                                int* __restrict__ goffs,
                                                int* __restrict__ gcur, int NB)
{
    __shared__ int s[1024];
    int t = threadIdx.x;
    int v = (t < NB) ? gcount[t] : 0;
    s[t] = v; __syncthreads();
    for (int d = 1; d < 1024; d <<= 1) {
        int x = (t >= d) ? s[t - d] : 0;
        __syncthreads();
        s[t] += x;
        __syncthreads();
    }
    if (t < NB) { int o = s[t] - v; goffs[t] = o; gcur[t] = o; }
    if (t == NB - 1) goffs[NB] = s[t];
}

__global__ __launch_bounds__(256) void bfill_k(const int* __restrict__ esrc,
                                               const int* __restrict__ edst,
                                               int* __restrict__ gcur,
                                               u32* __restrict__ bpacked, int E, int NB)
{
    __shared__ int lh[1024];
    __shared__ int lbase[1024];
    int t = threadIdx.x;
    for (int i = t; i < 1024; i += 256) lh[i] = 0;
    __syncthreads();
    int per = (E + gridDim.x - 1) / gridDim.x;
    int lo = blockIdx.x * per;
    int hi = lo + per; if (hi > E) hi = E;
    for (int e = lo + t; e < hi; e += 256) atomicAdd(&lh[edst[e] >> 7], 1);
    __syncthreads();
    for (int b = t; b < NB; b += 256) {
        int c = lh[b];
        lbase[b] = c ? atomicAdd(&gcur[b], c) : 0;
    }
    __syncthreads();
    for (int i = t; i < 1024; i += 256) lh[i] = 0;   // reuse as local cursor
    __syncthreads();
    for (int e = lo + t; e < hi; e += 256) {
        int d = edst[e];
        int b = d >> 7;
        int idx = atomicAdd(&lh[b], 1);
        bpacked[lbase[b] + idx] = ((u32)(d & 127) << 17) | (u32)esrc[e];
    }
}

// ---------------------------------------------------------------------------
// fine counting sort within each bucket -> dst-sorted slots + per-row offs/deg
// ---------------------------------------------------------------------------
__global__ __launch_bounds__(256) void fsort_k(const u32* __restrict__ bpacked,
                                               const int* __restrict__ goffs,
                                               int* __restrict__ slots,
                                               int* __restrict__ offs,
                                               int* __restrict__ deg, int N)
{
    __shared__ int cnt[128];
    __shared__ int roff[128];
    int b = blockIdx.x, t = threadIdx.x;
    int start = goffs[b], end = goffs[b + 1];
    if (t < 128) cnt[t] = 0;
    __syncthreads();
    for (int e = start + t; e < end; e += 256)
        atomicAdd(&cnt[bpacked[e] >> 17], 1);
    __syncthreads();
    if (t == 0) {
        int acc = 0;
        for (int i = 0; i < 128; ++i) { roff[i] = acc; acc += cnt[i]; }
    }
    __syncthreads();
    int row0 = b * 128;
    if (t < 128 && row0 + t < N) {
        offs[row0 + t] = start + roff[t];
        deg[row0 + t]  = cnt[t];
    }
    if (t < 128) cnt[t] = 0;   // reuse as cursor
    __syncthreads();
    for (int e = start + t; e < end; e += 256) {
        u32 pk = bpacked[e];
        int local = (int)(pk >> 17);
        int idx = atomicAdd(&cnt[local], 1);
        slots[start + roff[local] + idx] = (int)(pk & 0x1FFFF);
    }
}

// ---------------------------------------------------------------------------
// gather-aggregate: ONE wave per row (round-8 shape, occupancy ~71%), but
// 16-deep load batches: a typical deg~16 row is ONE memory round-trip.
// Full 16-groups unmasked; ragged tail = single masked 16-group (predicated
// adds, safe slot 0) -> no serial per-edge remainder.
// MODE 0: xa[row] = bf16( x[row] + sum_nbr x[s] )
// MODE 1: prev-layer BN folded in: xa[row] = bf16( sc.(h+sum) + (deg+1).sh )
// ---------------------------------------------------------------------------
template<int MODE>
__global__ __launch_bounds__(256) void gather_k(const u32* __restrict__ xb2,
                                                const int* __restrict__ offs,
                                                const int* __restrict__ deg,
                                                const int* __restrict__ slots,
                                                const float* __restrict__ stats_in,
                                                const float* __restrict__ g_in,
                                                const float* __restrict__ be_in,
                                                u32* __restrict__ xa2, int N)
{
    __shared__ float sc[128], sh[128];
    int t = threadIdx.x;
    if (MODE == 1) {
        if (t < 128) {
            float invN = 1.0f / (float)N;
            float mean = stats_in[t] * invN;
            float var  = stats_in[128 + t] * invN - mean * mean;
            float s = g_in[t] * rsqrtf(var + 1e-5f);
            sc[t] = s;
            sh[t] = be_in[t] - mean * s;
        }
        __syncthreads();
    }

    int row = blockIdx.x * 4 + (t >> 6);
    if (row >= N) return;
    int lane = t & 63;

    u32 self = xb2[(size_t)row * 64 + lane];
    float ax0 = bf_lo(self), ay0 = bf_hi(self);
    float ax1 = 0.f, ay1 = 0.f, ax2 = 0.f, ay2 = 0.f, ax3 = 0.f, ay3 = 0.f;

    int start = offs[row];
    int dg = deg[row];
    for (int base = 0; base < dg; base += 64) {
        int rem = dg - base;
        int m = rem < 64 ? rem : 64;
        int slot = (lane < m) ? slots[start + base + lane] : 0;
        int j = 0;
        for (; j + 16 <= m; j += 16) {   // full groups: 16 loads in flight
            int t0 = __shfl(slot, j + 0),  t1 = __shfl(slot, j + 1);
            int t2 = __shfl(slot, j + 2),  t3 = __shfl(slot, j + 3);
            int t4 = __shfl(slot, j + 4),  t5 = __shfl(slot, j + 5);
            int t6 = __shfl(slot, j + 6),  t7 = __shfl(slot, j + 7);
            int t8 = __shfl(slot, j + 8),  t9 = __shfl(slot, j + 9);
            int tA = __shfl(slot, j + 10), tB = __shfl(slot, j + 11);
            int tC = __shfl(slot, j + 12), tD = __shfl(slot, j + 13);
            int tE = __shfl(slot, j + 14), tF = __shfl(slot, j + 15);
            u32 v0 = xb2[(size_t)t0 * 64 + lane], v1 = xb2[(size_t)t1 * 64 + lane];
            u32 v2 = xb2[(size_t)t2 * 64 + lane], v3 = xb2[(size_t)t3 * 64 + lane];
            u32 v4 = xb2[(size_t)t4 * 64 + lane], v5 = xb2[(size_t)t5 * 64 + lane];
            u32 v6 = xb2[(size_t)t6 * 64 + lane], v7 = xb2[(size_t)t7 * 64 + lane];
            u32 v8 = xb2[(size_t)t8 * 64 + lane], v9 = xb2[(size_t)t9 * 64 + lane];
            u32 vA = xb2[(size_t)tA * 64 + lane], vB = xb2[(size_t)tB * 64 + lane];
            u32 vC = xb2[(size_t)tC * 64 + lane], vD = xb2[(size_t)tD * 64 + lane];
            u32 vE = xb2[(size_t)tE * 64 + lane], vF = xb2[(size_t)tF * 64 + lane];
            ax0 += bf_lo(v0); ay0 += bf_hi(v0);  ax1 += bf_lo(v1); ay1 += bf_hi(v1);
            ax2 += bf_lo(v2); ay2 += bf_hi(v2);  ax3 += bf_lo(v3); ay3 += bf_hi(v3);
            ax0 += bf_lo(v4); ay0 += bf_hi(v4);  ax1 += bf_lo(v5); ay1 += bf_hi(v5);
            ax2 += bf_lo(v6); ay2 += bf_hi(v6);  ax3 += bf_lo(v7); ay3 += bf_hi(v7);
            ax0 += bf_lo(v8); ay0 += bf_hi(v8);  ax1 += bf_lo(v9); ay1 += bf_hi(v9);
            ax2 += bf_lo(vA); ay2 += bf_hi(vA);  ax3 += bf_lo(vB); ay3 += bf_hi(vB);
            ax0 += bf_lo(vC); ay0 += bf_hi(vC);  ax1 += bf_lo(vD); ay1 += bf_hi(vD);
            ax2 += bf_lo(vE); ay2 += bf_hi(vE);  ax3 += bf_lo(vF); ay3 += bf_hi(vF);
        }
        if (j < m) {   // ragged tail: one masked 16-group (slot 0 is safe/hot)
            int t0 = __shfl(slot, j + 0),  t1 = __shfl(slot, j + 1);
            int t2 = __shfl(slot, j + 2),  t3 = __shfl(slot, j + 3);
            int t4 = __shfl(slot, j + 4),  t5 = __shfl(slot, j + 5);
            int t6 = __shfl(slot, j + 6),  t7 = __shfl(slot, j + 7);
            int t8 = __shfl(slot, j + 8),  t9 = __shfl(slot, j + 9);
            int tA = __shfl(slot, j + 10), tB = __shfl(slot, j + 11);
            int tC = __shfl(slot, j + 12), tD = __shfl(slot, j + 13);
            int tE = __shfl(slot, j + 14), tF = __shfl(slot, j + 15);
            u32 v0 = xb2[(size_t)t0 * 64 + lane], v1 = xb2[(size_t)t1 * 64 + lane];
            u32 v2 = xb2[(size_t)t2 * 64 + lane], v3 = xb2[(size_t)t3 * 64 + lane];
            u32 v4 = xb2[(size_t)t4 * 64 + lane], v5 = xb2[(size_t)t5 * 64 + lane];
            u32 v6 = xb2[(size_t)t6 * 64 + lane], v7 = xb2[(size_t)t7 * 64 + lane];
            u32 v8 = xb2[(size_t)t8 * 64 + lane], v9 = xb2[(size_t)t9 * 64 + lane];
            u32 vA = xb2[(size_t)tA * 64 + lane], vB = xb2[(size_t)tB * 64 + lane];
            u32 vC = xb2[(size_t)tC * 64 + lane], vD = xb2[(size_t)tD * 64 + lane];
            u32 vE = xb2[(size_t)tE * 64 + lane], vF = xb2[(size_t)tF * 64 + lane];
            ax0 += (j + 0  < m) ? bf_lo(v0) : 0.f;  ay0 += (j + 0  < m) ? bf_hi(v0) : 0.f;
            ax1 += (j + 1  < m) ? bf_lo(v1) : 0.f;  ay1 += (j + 1  < m) ? bf_hi(v1) : 0.f;
            ax2 += (j + 2  < m) ? bf_lo(v2) : 0.f;  ay2 += (j + 2  < m) ? bf_hi(v2) : 0.f;
            ax3 += (j + 3  < m) ? bf_lo(v3) : 0.f;  ay3 += (j + 3  < m) ? bf_hi(v3) : 0.f;
            ax0 += (j + 4  < m) ? bf_lo(v4) : 0.f;  ay0 += (j + 4  < m) ? bf_hi(v4) : 0.f;
            ax1 += (j + 5  < m) ? bf_lo(v5) : 0.f;  ay1 += (j + 5  < m) ? bf_hi(v5) : 0.f;
            ax2 += (j + 6  < m) ? bf_lo(v6) : 0.f;  ay2 += (j + 6  < m) ? bf_hi(v6) : 0.f;
            ax3 += (j + 7  < m) ? bf_lo(v7) : 0.f;  ay3 += (j + 7  < m) ? bf_hi(v7) : 0.f;
            ax0 += (j + 8  < m) ? bf_lo(v8) : 0.f;  ay0 += (j + 8  < m) ? bf_hi(v8) : 0.f;
            ax1 += (j + 9  < m) ? bf_lo(v9) : 0.f;  ay1 += (j + 9  < m) ? bf_hi(v9) : 0.f;
            ax2 += (j + 10 < m) ? bf_lo(vA) : 0.f;  ay2 += (j + 10 < m) ? bf_hi(vA) : 0.f;
            ax3 += (j + 11 < m) ? bf_lo(vB) : 0.f;  ay3 += (j + 11 < m) ? bf_hi(vB) : 0.f;
            ax0 += (j + 12 < m) ? bf_lo(vC) : 0.f;  ay0 += (j + 12 < m) ? bf_hi(vC) : 0.f;
            ax1 += (j + 13 < m) ? bf_lo(vD) : 0.f;  ay1 += (j + 13 < m) ? bf_hi(vD) : 0.f;
            ax2 += (j + 14 < m) ? bf_lo(vE) : 0.f;  ay2 += (j + 14 < m) ? bf_hi(vE) : 0.f;
            ax3 += (j + 15 < m) ? bf_lo(vF) : 0.f;  ay3 += (j + 15 < m) ? bf_hi(vF) : 0.f;
        }
    }
    float ax = (ax0 + ax1) + (ax2 + ax3);
    float ay = (ay0 + ay1) + (ay2 + ay3);
    if (MODE == 1) {
        float d1 = (float)(dg + 1);
        ax = sc[2 * lane]     * ax + d1 * sh[2 * lane];
        ay = sc[2 * lane + 1] * ay + d1 * sh[2 * lane + 1];
    }
    xa2[(size_t)row * 64 + lane] = pack2(ax, ay);
}

// ---------------------------------------------------------------------------
// fused MFMA MLP: h = relu(relu(XA@Wa + ba)@Wb + bb).
// BN stats -> per-block partial (coalesced store; no contended atomics).
// MODE 0: store bf16 h1.  MODE 1: store f32 h2.
// ---------------------------------------------------------------------------
template<int MODE>
__global__ __launch_bounds__(256) void mlp_mfma_k(
    const u16* __restrict__ xa,
    const u16* __restrict__ wfa, const float* __restrict__ ba,
    const u16* __restrict__ wfb, const float* __restrict__ bb,
    u16* __restrict__ hb_out, float* __restrict__ hf_out,
    float* __restrict__ partial, int N)
{
    __shared__ short ta[64 * 128];   // 16 KB tile (bf16, swizzled), reused
    __shared__ float ssum[256];

    int t = threadIdx.x;
    int w = t >> 6, l = t & 63;
    int row0 = blockIdx.x * 64;

    // stage XA tile (swizzled)
    for (int c = t; c < 1024; c += 256) {
        int r = c >> 4, ci = c & 15;
        int dst = (r * 128 + ci * 8) ^ ((r & 7) << 3);
        f32x4 v;
        if (row0 + r < N)
            v = *reinterpret_cast<const f32x4*>(xa + ((size_t)(row0 + r) * 128 + ci * 8));
        else
            v = f32x4{0.f, 0.f, 0.f, 0.f};
        *reinterpret_cast<f32x4*>(ta + dst) = v;
    }

    // W1 fragments for this wave's two 16-col blocks
    bf16x8 wf[2][4];
#pragma unroll
    for (int nr = 0; nr < 2; ++nr) {
        int nb = 2 * w + nr;
#pragma unroll
        for (int kg = 0; kg < 4; ++kg)
            wf[nr][kg] = *reinterpret_cast<const bf16x8*>(
                wfa + ((size_t)((kg * 8 + nb) * 64 + l)) * 8);
    }
    __syncthreads();

    int rr = l & 15;       // row within 16-tile
    int kg8 = l >> 4;      // k sub-group

    f32x4 acc[4][2];
#pragma unroll
    for (int mr = 0; mr < 4; ++mr)
#pragma unroll
        for (int nr = 0; nr < 2; ++nr)
            acc[mr][nr] = f32x4{0.f, 0.f, 0.f, 0.f};

#pragma unroll
    for (int mr = 0; mr < 4; ++mr) {
        int r = mr * 16 + rr;
        bf16x8 af[4];
#pragma unroll
        for (int kg = 0; kg < 4; ++kg) {
            int idx = (r * 128 + kg * 32 + kg8 * 8) ^ ((r & 7) << 3);
            af[kg] = *reinterpret_cast<const bf16x8*>(ta + idx);
        }
#pragma unroll
        for (int nr = 0; nr < 2; ++nr)
#pragma unroll
            for (int kg = 0; kg < 4; ++kg)
                acc[mr][nr] = __builtin_amdgcn_mfma_f32_16x16x32_bf16(
                    af[kg], wf[nr][kg], acc[mr][nr], 0, 0, 0);
    }
    __syncthreads();   // all GEMM1 reads of ta complete

    // bias + relu -> back into ta (bf16, swizzled)
    int colb = w * 32;
    float b0 = ba[colb + rr];
    float b1 = ba[colb + 16 + rr];
#pragma unroll
    for (int mr = 0; mr < 4; ++mr)
#pragma unroll
        for (int nr = 0; nr < 2; ++nr) {
            float bb_ = nr ? b1 : b0;
            int col = colb + nr * 16 + rr;
#pragma unroll
            for (int reg = 0; reg < 4; ++reg) {
                int row = mr * 16 + kg8 * 4 + reg;
                float v = fmaxf(acc[mr][nr][reg] + bb_, 0.0f);
                ta[(row * 128 + col) ^ ((row & 7) << 3)] = (short)f2bf(v);
            }
        }

    // W2 fragments
#pragma unroll
    for (int nr = 0; nr < 2; ++nr) {
        int nb = 2 * w + nr;
#pragma unroll
        for (int kg = 0; kg < 4; ++kg)
            wf[nr][kg] = *reinterpret_cast<const bf16x8*>(
                wfb + ((size_t)((kg * 8 + nb) * 64 + l)) * 8);
    }
    __syncthreads();   // intermediate tile fully written

#pragma unroll
    for (int mr = 0; mr < 4; ++mr)
#pragma unroll
        for (int nr = 0; nr < 2; ++nr)
            acc[mr][nr] = f32x4{0.f, 0.f, 0.f, 0.f};

#pragma unroll
    for (int mr = 0; mr < 4; ++mr) {
        int r = mr * 16 + rr;
        bf16x8 af[4];
#pragma unroll
        for (int kg = 0; kg < 4; ++kg) {
            int idx = (r * 128 + kg * 32 + kg8 * 8) ^ ((r & 7) << 3);
            af[kg] = *reinterpret_cast<const bf16x8*>(ta + idx);
        }
#pragma unroll
        for (int nr = 0; nr < 2; ++nr)
#pragma unroll
            for (int kg = 0; kg < 4; ++kg)
                acc[mr][nr] = __builtin_amdgcn_mfma_f32_16x16x32_bf16(
                    af[kg], wf[nr][kg], acc[mr][nr], 0, 0, 0);
    }

    // bias + relu + store + per-block BN stat partial
    float c0 = bb[colb + rr];
    float c1 = bb[colb + 16 + rr];
    float s0 = 0.f, q0 = 0.f, s1 = 0.f, q1 = 0.f;
#pragma unroll
    for (int mr = 0; mr < 4; ++mr) {
#pragma unroll
        for (int reg = 0; reg < 4; ++reg) {
            int row = row0 + mr * 16 + kg8 * 4 + reg;
            bool ok = row < N;
            float v0 = fmaxf(acc[mr][0][reg] + c0, 0.0f);
            float v1 = fmaxf(acc[mr][1][reg] + c1, 0.0f);
            if (ok) {
                if (MODE == 0) {
                    hb_out[(size_t)row * 128 + colb + rr]      = f2bf(v0);
                    hb_out[(size_t)row * 128 + colb + 16 + rr] = f2bf(v1);
                } else {
                    hf_out[(size_t)row * 128 + colb + rr]      = v0;
                    hf_out[(size_t)row * 128 + colb + 16 + rr] = v1;
                }
                s0 += v0; q0 += v0 * v0;
                s1 += v1; q1 += v1 * v1;
            }
        }
    }
    s0 += __shfl_xor(s0, 16); s0 += __shfl_xor(s0, 32);
    q0 += __shfl_xor(q0, 16); q0 += __shfl_xor(q0, 32);
    s1 += __shfl_xor(s1, 16); s1 += __shfl_xor(s1, 32);
    q1 += __shfl_xor(q1, 16); q1 += __shfl_xor(q1, 32);
    if (kg8 == 0) {            // each column owned by exactly one lane
        ssum[colb + rr]            = s0;
        ssum[128 + colb + rr]      = q0;
        ssum[colb + 16 + rr]       = s1;
        ssum[128 + colb + 16 + rr] = q1;
    }
    __syncthreads();
    partial[(size_t)blockIdx.x * 256 + t] = ssum[t];   // coalesced, no atomics
}

// ---------------------------------------------------------------------------
// reduce partials (nrows x 256) -> stats[256]; 32 blocks, 32 atomics/address
// ---------------------------------------------------------------------------
__global__ __launch_bounds__(256) void reduce_k(const float* __restrict__ partial,
                                                float* __restrict__ stats, int nrows)
{
    int t = threadIdx.x;
    int chunk = (nrows + gridDim.x - 1) / gridDim.x;
    int lo = blockIdx.x * chunk;
    int hi = lo + chunk; if (hi > nrows) hi = nrows;
    float acc = 0.f;
    for (int r = lo; r < hi; ++r)
        acc += partial[(size_t)r * 256 + t];
    if (hi > lo) atomicAdd(&stats[t], acc);
}

// ---------------------------------------------------------------------------
// final BN: in-place f32 on d_out
// ---------------------------------------------------------------------------
__global__ __launch_bounds__(256) void bn_apply_k(
    float* __restrict__ h, const float* __restrict__ stats,
    const float* __restrict__ gamma, const float* __restrict__ beta, int N)
{
    __shared__ float sc[128], sh[128];
    int t = threadIdx.x;
    if (t < 128) {
        float invN = 1.0f / (float)N;
        float mean = stats[t] * invN;
        float var  = stats[128 + t] * invN - mean * mean;
        float s = gamma[t] * rsqrtf(var + 1e-5f);
        sc[t] = s;
        sh[t] = beta[t] - mean * s;
    }
    __syncthreads();
    int total = N * 32;
    for (int i = blockIdx.x * 256 + t; i < total; i += gridDim.x * 256) {
        float4 v = reinterpret_cast<float4*>(h)[i];
        int c = (i & 31) * 4;
        v.x = v.x * sc[c + 0] + sh[c + 0];
        v.y = v.y * sc[c + 1] + sh[c + 1];
        v.z = v.z * sc[c + 2] + sh[c + 2];
        v.w = v.w * sc[c + 3] + sh[c + 3];
        reinterpret_cast<float4*>(h)[i] = v;
    }
}

// ---------------------------------------------------------------------------
extern "C" void kernel_launch(void* const* d_in, const int* in_sizes, int n_in,
                              void* d_out, int out_size, void* d_ws, size_t ws_size,
                              hipStream_t stream)
{
    const float* x   = (const float*)d_in[0];
    const int*   ei  = (const int*)d_in[1];
    const float* W1a = (const float*)d_in[2];
    const float* b1a = (const float*)d_in[3];
    const float* W1b = (const float*)d_in[4];
    const float* b1b = (const float*)d_in[5];
    const float* g1  = (const float*)d_in[6];
    const float* be1 = (const float*)d_in[7];
    const float* W2a = (const float*)d_in[8];
    const float* b2a = (const float*)d_in[9];
    const float* W2b = (const float*)d_in[10];
    const float* b2b = (const float*)d_in[11];
    const float* g2  = (const float*)d_in[12];
    const float* be2 = (const float*)d_in[13];

    const int N = in_sizes[0] / 128;
    const int E = in_sizes[1] / 2;
    const int* esrc = ei;
    const int* edst = ei + E;
    const int NB = (N + 127) >> 7;   // 128-row buckets; requires N <= 131072

    const int mblocks = (N + 63) / 64;
    const int gblocks = (N + 3) / 4;   // 1 row/wave, 4 rows/block

    // ---- workspace carve ----
    char* p = (char*)d_ws;
    const size_t featb = (size_t)N * 128 * sizeof(u16);     // 25.6 MB
    u16* xa = (u16*)p;            p += featb;               // gather output
    u16* h1 = (u16*)p;            p += featb;               // layer-1 bf16 output
    u16* xb = (u16*)p;            p += featb;               // bf16 input features
    u16* wf = (u16*)p;            p += 4 * 16384 * sizeof(u16);
    int* slots = (int*)p;         p += (size_t)E * sizeof(int);
    int* deg   = (int*)p;         p += (size_t)N * sizeof(int);
    int* offs  = (int*)p;         p += (size_t)N * sizeof(int);
    int* gcount = (int*)p;        p += 1024 * sizeof(int);
    int* goffs  = (int*)p;        p += 1032 * sizeof(int);
    int* gcur   = (int*)p;        p += 1024 * sizeof(int);
    float* stats = (float*)p;     p += 512 * sizeof(float);
    float* partial = (float*)p;   p += (size_t)mblocks * 256 * sizeof(float);
    u32* bpacked = (u32*)xa;      // alias (E*4 = 6.4MB <= featb), dead early

    u16* wf1a = wf;
    u16* wf1b = wf + 16384;
    u16* wf2a = wf + 32768;
    u16* wf2b = wf + 49152;
    float* stats1 = stats;
    float* stats2 = stats + 256;

    float* h = (float*)d_out;

    // ---- one-time prep: bucket sort -> fine sort -> CSR; bf16 conversions ----
    hipMemsetAsync(gcount, 0, 1024 * sizeof(int), stream);
    bhist_k<<<256, 256, 0, stream>>>(edst, gcount, E, NB);
    bscan_k<<<1, 1024, 0, stream>>>(gcount, goffs, gcur, NB);
    bfill_k<<<256, 256, 0, stream>>>(esrc, edst, gcur, bpacked, E, NB);
    fsort_k<<<NB, 256, 0, stream>>>(bpacked, goffs, slots, offs, deg, N);
    convert_k<<<2048, 256, 0, stream>>>(x, (u32*)xb, N * 32);
    wprep_k<<<256, 256, 0, stream>>>(W1a, W1b, W2a, W2b, wf);
    hipMemsetAsync(stats, 0, 512 * sizeof(float), stream);

    // ---- layer 1: gather -> MLP (bf16 h1 + partial) -> reduce stats1 ----
    gather_k<0><<<gblocks, 256, 0, stream>>>((const u32*)xb, offs, deg, slots,
                                             nullptr, nullptr, nullptr, (u32*)xa, N);
    mlp_mfma_k<0><<<mblocks, 256, 0, stream>>>(xa, wf1a, b1a, wf1b, b1b,
                                               h1, (float*)nullptr, partial, N);
    reduce_k<<<32, 256, 0, stream>>>(partial, stats1, mblocks);

    // ---- layer 2: gather (BN1 folded) -> MLP (f32 h + partial) -> stats2 ----
    gather_k<1><<<gblocks, 256, 0, stream>>>((const u32*)h1, offs, deg, slots,
                                             stats1, g1, be1, (u32*)xa, N);
    mlp_mfma_k<1><<<mblocks, 256, 0, stream>>>(xa, wf2a, b2a, wf2b, b2b,
                                               (u16*)nullptr, h, partial, N);
    reduce_k<<<32, 256, 0, stream>>>(partial, stats2, mblocks);

    // ---- final BN in place on d_out ----
    bn_apply_k<<<2048, 256, 0, stream>>>(h, stats2, g2, be2, N);
}

// Round 11
// 281.906 us; speedup vs baseline: 1.1028x; 1.0581x over previous
//
#include <hip/hip_runtime.h>
#include <hip/hip_bf16.h>

typedef unsigned int u32;
typedef unsigned short u16;
typedef short bf16x8 __attribute__((ext_vector_type(8)));
typedef float f32x4 __attribute__((ext_vector_type(4)));

static __device__ __forceinline__ float bf_lo(u32 v) { return __uint_as_float(v << 16); }
static __device__ __forceinline__ float bf_hi(u32 v) { return __uint_as_float(v & 0xffff0000u); }
static __device__ __forceinline__ u16 f2bf(float f) {
    u32 u = __float_as_uint(f);
    u32 r = u + 0x7fffu + ((u >> 16) & 1u);   // RNE; inputs finite
    return (u16)(r >> 16);
}
static __device__ __forceinline__ u32 pack2(float a, float b) {
    return ((u32)f2bf(b) << 16) | (u32)f2bf(a);
}

// ---------------------------------------------------------------------------
// f32 -> bf16 convert (row-major, packed pairs)
// ---------------------------------------------------------------------------
__global__ __launch_bounds__(256) void convert_k(const float* __restrict__ in,
                                                 u32* __restrict__ out2, int total4)
{
    for (int i = blockIdx.x * 256 + threadIdx.x; i < total4; i += gridDim.x * 256) {
        float4 v = reinterpret_cast<const float4*>(in)[i];
        out2[2 * i + 0] = pack2(v.x, v.y);
        out2[2 * i + 1] = pack2(v.z, v.w);
    }
}

// ---------------------------------------------------------------------------
// weight prep (all 4 mats in one launch): W (128x128 f32, row-major W[k][n])
// -> fragment-ordered bf16
// ---------------------------------------------------------------------------
__global__ __launch_bounds__(256) void wprep_k(const float* __restrict__ Wa,
                                               const float* __restrict__ Wb,
                                               const float* __restrict__ Wc,
                                               const float* __restrict__ Wd,
                                               u16* __restrict__ Wf)
{
    int g = blockIdx.x * 256 + threadIdx.x;   // 0..65535
    int which = g >> 14;
    int t = g & 16383;
    const float* W = which == 0 ? Wa : which == 1 ? Wb : which == 2 ? Wc : Wd;
    int j  = t & 7;
    int l  = (t >> 3) & 63;
    int nb = (t >> 9) & 7;
    int kg = (t >> 12) & 3;
    int k  = kg * 32 + (l >> 4) * 8 + j;
    int n  = nb * 16 + (l & 15);
    Wf[g] = f2bf(W[k * 128 + n]);
}

// ---------------------------------------------------------------------------
// Coarse bucket sort by dst>>7 (128 rows/bucket). NB <= 1024, N <= 131072.
// packed edge: (dst&127)<<17 | src
// ---------------------------------------------------------------------------
__global__ __launch_bounds__(256) void bhist_k(const int* __restrict__ edst,
                                               int* __restrict__ gcount, int E, int NB)
{
    __shared__ int lh[1024];
    for (int i = threadIdx.x; i < 1024; i += 256) lh[i] = 0;
    __syncthreads();
    for (int e = blockIdx.x * 256 + threadIdx.x; e < E; e += gridDim.x * 256)
        atomicAdd(&lh[edst[e] >> 7], 1);
    __syncthreads();
    for (int b = threadIdx.x; b < NB; b += 256)
        if (lh[b]) atomicAdd(&gcount[b], lh[b]);
}

__global__ __launch_bounds__(1024) void bscan_k(const int* __restrict__ gcount,
                                                int* __restrict__ goffs,
                                                int* __restrict__ gcur, int NB)
{
    __shared__ int s[1024];
    int t = threadIdx.x;
    int v = (t < NB) ? gcount[t] : 0;
    s[t] = v; __syncthreads();
    for (int d = 1; d < 1024; d <<= 1) {
        int x = (t >= d) ? s[t - d] : 0;
        __syncthreads();
        s[t] += x;
        __syncthreads();
    }
    if (t < NB) { int o = s[t] - v; goffs[t] = o; gcur[t] = o; }
    if (t == NB - 1) goffs[NB] = s[t];
}

__global__ __launch_bounds__(256) void bfill_k(const int* __restrict__ esrc,
                                               const int* __restrict__ edst,
                                               int* __restrict__ gcur,
                                               u32* __restrict__ bpacked, int E, int NB)
{
    __shared__ int lh[1024];
    __shared__ int lbase[1024];
    int t = threadIdx.x;
    for (int i = t; i < 1024; i += 256) lh[i] = 0;
    __syncthreads();
    int per = (E + gridDim.x - 1) / gridDim.x;
    int lo = blockIdx.x * per;
    int hi = lo + per; if (hi > E) hi = E;
    for (int e = lo + t; e < hi; e += 256) atomicAdd(&lh[edst[e] >> 7], 1);
    __syncthreads();
    for (int b = t; b < NB; b += 256) {
        int c = lh[b];
        lbase[b] = c ? atomicAdd(&gcur[b], c) : 0;
    }
    __syncthreads();
    for (int i = t; i < 1024; i += 256) lh[i] = 0;   // reuse as local cursor
    __syncthreads();
    for (int e = lo + t; e < hi; e += 256) {
        int d = edst[e];
        int b = d >> 7;
        int idx = atomicAdd(&lh[b], 1);
        bpacked[lbase[b] + idx] = ((u32)(d & 127) << 17) | (u32)esrc[e];
    }
}

// ---------------------------------------------------------------------------
// fine counting sort within each bucket -> dst-sorted slots + per-row offs/deg
// (parallel Hillis-Steele scan instead of serial t==0 loop)
// ---------------------------------------------------------------------------
__global__ __launch_bounds__(256) void fsort_k(const u32* __restrict__ bpacked,
                                               const int* __restrict__ goffs,
                                               int* __restrict__ slots,
                                               int* __restrict__ offs,
                                               int* __restrict__ deg, int N)
{
    __shared__ int cnt[128];
    __shared__ int roff[128];
    __shared__ int sb[128];
    int b = blockIdx.x, t = threadIdx.x;
    int start = goffs[b], end = goffs[b + 1];
    if (t < 128) cnt[t] = 0;
    __syncthreads();
    for (int e = start + t; e < end; e += 256)
        atomicAdd(&cnt[bpacked[e] >> 17], 1);
    __syncthreads();
    if (t < 128) sb[t] = cnt[t];
    __syncthreads();
    for (int d = 1; d < 128; d <<= 1) {
        int x = (t < 128 && t >= d) ? sb[t - d] : 0;
        __syncthreads();
        if (t < 128) sb[t] += x;
        __syncthreads();
    }
    if (t < 128) roff[t] = sb[t] - cnt[t];   // exclusive prefix
    __syncthreads();
    int row0 = b * 128;
    if (t < 128 && row0 + t < N) {
        offs[row0 + t] = start + roff[t];
        deg[row0 + t]  = cnt[t];
    }
    if (t < 128) cnt[t] = 0;   // reuse as cursor
    __syncthreads();
    for (int e = start + t; e < end; e += 256) {
        u32 pk = bpacked[e];
        int local = (int)(pk >> 17);
        int idx = atomicAdd(&cnt[local], 1);
        slots[start + roff[local] + idx] = (int)(pk & 0x1FFFF);
    }
}

// ---------------------------------------------------------------------------
// gather-aggregate: one wave per row. All control state (offs/deg/slot
// indices) is wave-uniform -> hoisted to SGPRs via readfirstlane: slot
// fetches become s_load (one 64B K$ line per 16 edges) and row loads become
// saddr-form global_load with 0 VALU of per-edge address math. ~4 VALU/edge.
// MODE 0: xa[row] = bf16( x[row] + sum_nbr x[s] )
// MODE 1: prev-layer BN folded in: xa[row] = bf16( sc.(h+sum) + (deg+1).sh )
// ---------------------------------------------------------------------------
#define ROWP(s) reinterpret_cast<const u32*>(xbase + ((size_t)(u32)(s) << 8))

template<int MODE>
__global__ __launch_bounds__(256) void gather_k(const u32* __restrict__ xb2,
                                                const int* __restrict__ offs,
                                                const int* __restrict__ deg,
                                                const int* __restrict__ slots,
                                                const float* __restrict__ stats_in,
                                                const float* __restrict__ g_in,
                                                const float* __restrict__ be_in,
                                                u32* __restrict__ xa2, int N)
{
    __shared__ float sc[128], sh[128];
    int t = threadIdx.x;
    if (MODE == 1) {
        if (t < 128) {
            float invN = 1.0f / (float)N;
            float mean = stats_in[t] * invN;
            float var  = stats_in[128 + t] * invN - mean * mean;
            float s = g_in[t] * rsqrtf(var + 1e-5f);
            sc[t] = s;
            sh[t] = be_in[t] - mean * s;
        }
        __syncthreads();
    }

    int row = blockIdx.x * 4 + (t >> 6);
    if (row >= N) return;
    int lane = t & 63;
    const char* xbase = (const char*)xb2;

    u32 self = ROWP(row)[lane];
    float ax0 = bf_lo(self), ay0 = bf_hi(self);
    float ax1 = 0.f, ay1 = 0.f, ax2 = 0.f, ay2 = 0.f, ax3 = 0.f, ay3 = 0.f;

    // wave-uniform CSR state -> SGPRs
    int ustart = __builtin_amdgcn_readfirstlane(offs[row]);
    int udg    = __builtin_amdgcn_readfirstlane(deg[row]);

    int e = 0;
    for (; e + 16 <= udg; e += 16) {   // scalar slot fetch, 16 loads in flight
        int s0 = slots[ustart + e + 0],  s1 = slots[ustart + e + 1];
        int s2 = slots[ustart + e + 2],  s3 = slots[ustart + e + 3];
        int s4 = slots[ustart + e + 4],  s5 = slots[ustart + e + 5];
        int s6 = slots[ustart + e + 6],  s7 = slots[ustart + e + 7];
        int s8 = slots[ustart + e + 8],  s9 = slots[ustart + e + 9];
        int sA = slots[ustart + e + 10], sB = slots[ustart + e + 11];
        int sC = slots[ustart + e + 12], sD = slots[ustart + e + 13];
        int sE = slots[ustart + e + 14], sF = slots[ustart + e + 15];
        u32 v0 = ROWP(s0)[lane], v1 = ROWP(s1)[lane];
        u32 v2 = ROWP(s2)[lane], v3 = ROWP(s3)[lane];
        u32 v4 = ROWP(s4)[lane], v5 = ROWP(s5)[lane];
        u32 v6 = ROWP(s6)[lane], v7 = ROWP(s7)[lane];
        u32 v8 = ROWP(s8)[lane], v9 = ROWP(s9)[lane];
        u32 vA = ROWP(sA)[lane], vB = ROWP(sB)[lane];
        u32 vC = ROWP(sC)[lane], vD = ROWP(sD)[lane];
        u32 vE = ROWP(sE)[lane], vF = ROWP(sF)[lane];
        ax0 += bf_lo(v0); ay0 += bf_hi(v0);  ax1 += bf_lo(v1); ay1 += bf_hi(v1);
        ax2 += bf_lo(v2); ay2 += bf_hi(v2);  ax3 += bf_lo(v3); ay3 += bf_hi(v3);
        ax0 += bf_lo(v4); ay0 += bf_hi(v4);  ax1 += bf_lo(v5); ay1 += bf_hi(v5);
        ax2 += bf_lo(v6); ay2 += bf_hi(v6);  ax3 += bf_lo(v7); ay3 += bf_hi(v7);
        ax0 += bf_lo(v8); ay0 += bf_hi(v8);  ax1 += bf_lo(v9); ay1 += bf_hi(v9);
        ax2 += bf_lo(vA); ay2 += bf_hi(vA);  ax3 += bf_lo(vB); ay3 += bf_hi(vB);
        ax0 += bf_lo(vC); ay0 += bf_hi(vC);  ax1 += bf_lo(vD); ay1 += bf_hi(vD);
        ax2 += bf_lo(vE); ay2 += bf_hi(vE);  ax3 += bf_lo(vF); ay3 += bf_hi(vF);
    }
    if (e + 8 <= udg) {                // uniform 8-remainder
        int s0 = slots[ustart + e + 0], s1 = slots[ustart + e + 1];
        int s2 = slots[ustart + e + 2], s3 = slots[ustart + e + 3];
        int s4 = slots[ustart + e + 4], s5 = slots[ustart + e + 5];
        int s6 = slots[ustart + e + 6], s7 = slots[ustart + e + 7];
        u32 v0 = ROWP(s0)[lane], v1 = ROWP(s1)[lane];
        u32 v2 = ROWP(s2)[lane], v3 = ROWP(s3)[lane];
        u32 v4 = ROWP(s4)[lane], v5 = ROWP(s5)[lane];
        u32 v6 = ROWP(s6)[lane], v7 = ROWP(s7)[lane];
        ax0 += bf_lo(v0); ay0 += bf_hi(v0);  ax1 += bf_lo(v1); ay1 += bf_hi(v1);
        ax2 += bf_lo(v2); ay2 += bf_hi(v2);  ax3 += bf_lo(v3); ay3 += bf_hi(v3);
        ax0 += bf_lo(v4); ay0 += bf_hi(v4);  ax1 += bf_lo(v5); ay1 += bf_hi(v5);
        ax2 += bf_lo(v6); ay2 += bf_hi(v6);  ax3 += bf_lo(v7); ay3 += bf_hi(v7);
        e += 8;
    }
    if (e + 4 <= udg) {                // uniform 4-remainder
        int s0 = slots[ustart + e + 0], s1 = slots[ustart + e + 1];
        int s2 = slots[ustart + e + 2], s3 = slots[ustart + e + 3];
        u32 v0 = ROWP(s0)[lane], v1 = ROWP(s1)[lane];
        u32 v2 = ROWP(s2)[lane], v3 = ROWP(s3)[lane];
        ax0 += bf_lo(v0); ay0 += bf_hi(v0);  ax1 += bf_lo(v1); ay1 += bf_hi(v1);
        ax2 += bf_lo(v2); ay2 += bf_hi(v2);  ax3 += bf_lo(v3); ay3 += bf_hi(v3);
        e += 4;
    }
    for (; e < udg; ++e) {             // <=3 uniform iterations
        int s = slots[ustart + e];
        u32 v = ROWP(s)[lane];
        ax0 += bf_lo(v); ay0 += bf_hi(v);
    }

    float ax = (ax0 + ax1) + (ax2 + ax3);
    float ay = (ay0 + ay1) + (ay2 + ay3);
    if (MODE == 1) {
        float d1 = (float)(udg + 1);
        ax = sc[2 * lane]     * ax + d1 * sh[2 * lane];
        ay = sc[2 * lane + 1] * ay + d1 * sh[2 * lane + 1];
    }
    xa2[(size_t)row * 64 + lane] = pack2(ax, ay);
}

// ---------------------------------------------------------------------------
// fused MFMA MLP: h = relu(relu(XA@Wa + ba)@Wb + bb) -> bf16 out + partials.
// (d_out is now written only once, by bn_apply_bf_k.)
// ---------------------------------------------------------------------------
__global__ __launch_bounds__(256) void mlp_mfma_k(
    const u16* __restrict__ xa,
    const u16* __restrict__ wfa, const float* __restrict__ ba,
    const u16* __restrict__ wfb, const float* __restrict__ bb,
    u16* __restrict__ hb_out, float* __restrict__ partial, int N)
{
    __shared__ short ta[64 * 128];   // 16 KB tile (bf16, swizzled), reused
    __shared__ float ssum[256];

    int t = threadIdx.x;
    int w = t >> 6, l = t & 63;
    int row0 = blockIdx.x * 64;

    // stage XA tile (swizzled)
    for (int c = t; c < 1024; c += 256) {
        int r = c >> 4, ci = c & 15;
        int dst = (r * 128 + ci * 8) ^ ((r & 7) << 3);
        f32x4 v;
        if (row0 + r < N)
            v = *reinterpret_cast<const f32x4*>(xa + ((size_t)(row0 + r) * 128 + ci * 8));
        else
            v = f32x4{0.f, 0.f, 0.f, 0.f};
        *reinterpret_cast<f32x4*>(ta + dst) = v;
    }

    // W1 fragments
    bf16x8 wf[2][4];
#pragma unroll
    for (int nr = 0; nr < 2; ++nr) {
        int nb = 2 * w + nr;
#pragma unroll
        for (int kg = 0; kg < 4; ++kg)
            wf[nr][kg] = *reinterpret_cast<const bf16x8*>(
                wfa + ((size_t)((kg * 8 + nb) * 64 + l)) * 8);
    }
    __syncthreads();

    int rr = l & 15;
    int kg8 = l >> 4;

    f32x4 acc[4][2];
#pragma unroll
    for (int mr = 0; mr < 4; ++mr)
#pragma unroll
        for (int nr = 0; nr < 2; ++nr)
            acc[mr][nr] = f32x4{0.f, 0.f, 0.f, 0.f};

#pragma unroll
    for (int mr = 0; mr < 4; ++mr) {
        int r = mr * 16 + rr;
        bf16x8 af[4];
#pragma unroll
        for (int kg = 0; kg < 4; ++kg) {
            int idx = (r * 128 + kg * 32 + kg8 * 8) ^ ((r & 7) << 3);
            af[kg] = *reinterpret_cast<const bf16x8*>(ta + idx);
        }
#pragma unroll
        for (int nr = 0; nr < 2; ++nr)
#pragma unroll
            for (int kg = 0; kg < 4; ++kg)
                acc[mr][nr] = __builtin_amdgcn_mfma_f32_16x16x32_bf16(
                    af[kg], wf[nr][kg], acc[mr][nr], 0, 0, 0);
    }
    __syncthreads();   // all GEMM1 reads of ta complete

    // bias + relu -> back into ta
    int colb = w * 32;
    float b0 = ba[colb + rr];
    float b1 = ba[colb + 16 + rr];
#pragma unroll
    for (int mr = 0; mr < 4; ++mr)
#pragma unroll
        for (int nr = 0; nr < 2; ++nr) {
            float bb_ = nr ? b1 : b0;
            int col = colb + nr * 16 + rr;
#pragma unroll
            for (int reg = 0; reg < 4; ++reg) {
                int row = mr * 16 + kg8 * 4 + reg;
                float v = fmaxf(acc[mr][nr][reg] + bb_, 0.0f);
                ta[(row * 128 + col) ^ ((row & 7) << 3)] = (short)f2bf(v);
            }
        }

    // W2 fragments
#pragma unroll
    for (int nr = 0; nr < 2; ++nr) {
        int nb = 2 * w + nr;
#pragma unroll
        for (int kg = 0; kg < 4; ++kg)
            wf[nr][kg] = *reinterpret_cast<const bf16x8*>(
                wfb + ((size_t)((kg * 8 + nb) * 64 + l)) * 8);
    }
    __syncthreads();

#pragma unroll
    for (int mr = 0; mr < 4; ++mr)
#pragma unroll
        for (int nr = 0; nr < 2; ++nr)
            acc[mr][nr] = f32x4{0.f, 0.f, 0.f, 0.f};

#pragma unroll
    for (int mr = 0; mr < 4; ++mr) {
        int r = mr * 16 + rr;
        bf16x8 af[4];
#pragma unroll
        for (int kg = 0; kg < 4; ++kg) {
            int idx = (r * 128 + kg * 32 + kg8 * 8) ^ ((r & 7) << 3);
            af[kg] = *reinterpret_cast<const bf16x8*>(ta + idx);
        }
#pragma unroll
        for (int nr = 0; nr < 2; ++nr)
#pragma unroll
            for (int kg = 0; kg < 4; ++kg)
                acc[mr][nr] = __builtin_amdgcn_mfma_f32_16x16x32_bf16(
                    af[kg], wf[nr][kg], acc[mr][nr], 0, 0, 0);
    }

    // bias + relu + bf16 store + per-block BN stat partial
    float c0 = bb[colb + rr];
    float c1 = bb[colb + 16 + rr];
    float s0 = 0.f, q0 = 0.f, s1 = 0.f, q1 = 0.f;
#pragma unroll
    for (int mr = 0; mr < 4; ++mr) {
#pragma unroll
        for (int reg = 0; reg < 4; ++reg) {
            int row = row0 + mr * 16 + kg8 * 4 + reg;
            bool ok = row < N;
            float v0 = fmaxf(acc[mr][0][reg] + c0, 0.0f);
            float v1 = fmaxf(acc[mr][1][reg] + c1, 0.0f);
            if (ok) {
                hb_out[(size_t)row * 128 + colb + rr]      = f2bf(v0);
                hb_out[(size_t)row * 128 + colb + 16 + rr] = f2bf(v1);
                s0 += v0; q0 += v0 * v0;
                s1 += v1; q1 += v1 * v1;
            }
        }
    }
    s0 += __shfl_xor(s0, 16); s0 += __shfl_xor(s0, 32);
    q0 += __shfl_xor(q0, 16); q0 += __shfl_xor(q0, 32);
    s1 += __shfl_xor(s1, 16); s1 += __shfl_xor(s1, 32);
    q1 += __shfl_xor(q1, 16); q1 += __shfl_xor(q1, 32);
    if (kg8 == 0) {
        ssum[colb + rr]            = s0;
        ssum[128 + colb + rr]      = q0;
        ssum[colb + 16 + rr]       = s1;
        ssum[128 + colb + 16 + rr] = q1;
    }
    __syncthreads();
    partial[(size_t)blockIdx.x * 256 + t] = ssum[t];   // coalesced, no atomics
}

// ---------------------------------------------------------------------------
// reduce partials (nrows x 256) -> stats[256]
// ---------------------------------------------------------------------------
__global__ __launch_bounds__(256) void reduce_k(const float* __restrict__ partial,
                                                float* __restrict__ stats, int nrows)
{
    int t = threadIdx.x;
    int chunk = (nrows + gridDim.x - 1) / gridDim.x;
    int lo = blockIdx.x * chunk;
    int hi = lo + chunk; if (hi > nrows) hi = nrows;
    float acc = 0.f;
    for (int r = lo; r < hi; ++r)
        acc += partial[(size_t)r * 256 + t];
    if (hi > lo) atomicAdd(&stats[t], acc);
}

// ---------------------------------------------------------------------------
// final BN: read bf16 h2, write f32 d_out (single d_out write pass)
// ---------------------------------------------------------------------------
__global__ __launch_bounds__(256) void bn_apply_bf_k(
    const u32* __restrict__ h2b, const float* __restrict__ stats,
    const float* __restrict__ gamma, const float* __restrict__ beta,
    float* __restrict__ out, int N)
{
    __shared__ float sc[128], sh[128];
    int t = threadIdx.x;
    if (t < 128) {
        float invN = 1.0f / (float)N;
        float mean = stats[t] * invN;
        float var  = stats[128 + t] * invN - mean * mean;
        float s = gamma[t] * rsqrtf(var + 1e-5f);
        sc[t] = s;
        sh[t] = beta[t] - mean * s;
    }
    __syncthreads();
    int total2 = N * 64;   // u32 count
    for (int i = blockIdx.x * 256 + t; i < total2; i += gridDim.x * 256) {
        u32 v = h2b[i];
        int c = (i & 63) * 2;
        float2 o;
        o.x = bf_lo(v) * sc[c]     + sh[c];
        o.y = bf_hi(v) * sc[c + 1] + sh[c + 1];
        reinterpret_cast<float2*>(out)[i] = o;
    }
}

// ---------------------------------------------------------------------------
extern "C" void kernel_launch(void* const* d_in, const int* in_sizes, int n_in,
                              void* d_out, int out_size, void* d_ws, size_t ws_size,
                              hipStream_t stream)
{
    const float* x   = (const float*)d_in[0];
    const int*   ei  = (const int*)d_in[1];
    const float* W1a = (const float*)d_in[2];
    const float* b1a = (const float*)d_in[3];
    const float* W1b = (const float*)d_in[4];
    const float* b1b = (const float*)d_in[5];
    const float* g1  = (const float*)d_in[6];
    const float* be1 = (const float*)d_in[7];
    const float* W2a = (const float*)d_in[8];
    const float* b2a = (const float*)d_in[9];
    const float* W2b = (const float*)d_in[10];
    const float* b2b = (const float*)d_in[11];
    const float* g2  = (const float*)d_in[12];
    const float* be2 = (const float*)d_in[13];

    const int N = in_sizes[0] / 128;
    const int E = in_sizes[1] / 2;
    const int* esrc = ei;
    const int* edst = ei + E;
    const int NB = (N + 127) >> 7;   // 128-row buckets; requires N <= 131072

    const int mblocks = (N + 63) / 64;
    const int gblocks = (N + 3) / 4;   // 1 row/wave, 4 rows/block

    // ---- workspace carve ----
    char* p = (char*)d_ws;
    const size_t featb = (size_t)N * 128 * sizeof(u16);     // 25.6 MB
    u16* xa = (u16*)p;            p += featb;               // gather output
    u16* h1 = (u16*)p;            p += featb;               // layer-1/2 bf16 output
    u16* xb = (u16*)p;            p += featb;               // bf16 input features
    u16* wf = (u16*)p;            p += 4 * 16384 * sizeof(u16);
    int* slots = (int*)p;         p += (size_t)E * sizeof(int) + 64;  // +64B s_load overread pad
    int* deg   = (int*)p;         p += (size_t)N * sizeof(int);
    int* offs  = (int*)p;         p += (size_t)N * sizeof(int);
    int* gcount = (int*)p;        p += 1024 * sizeof(int);
    int* goffs  = (int*)p;        p += 1032 * sizeof(int);
    int* gcur   = (int*)p;        p += 1024 * sizeof(int);
    float* stats = (float*)p;     p += 512 * sizeof(float);
    float* partial = (float*)p;   p += (size_t)mblocks * 256 * sizeof(float);
    u32* bpacked = (u32*)xa;      // alias (E*4 = 6.4MB <= featb), dead early

    u16* wf1a = wf;
    u16* wf1b = wf + 16384;
    u16* wf2a = wf + 32768;
    u16* wf2b = wf + 49152;
    float* stats1 = stats;
    float* stats2 = stats + 256;

    float* h = (float*)d_out;

    // ---- one-time prep: bucket sort -> fine sort -> CSR; bf16 conversions ----
    hipMemsetAsync(gcount, 0, 1024 * sizeof(int), stream);
    bhist_k<<<256, 256, 0, stream>>>(edst, gcount, E, NB);
    bscan_k<<<1, 1024, 0, stream>>>(gcount, goffs, gcur, NB);
    bfill_k<<<256, 256, 0, stream>>>(esrc, edst, gcur, bpacked, E, NB);
    fsort_k<<<NB, 256, 0, stream>>>(bpacked, goffs, slots, offs, deg, N);
    convert_k<<<2048, 256, 0, stream>>>(x, (u32*)xb, N * 32);
    wprep_k<<<256, 256, 0, stream>>>(W1a, W1b, W2a, W2b, wf);
    hipMemsetAsync(stats, 0, 512 * sizeof(float), stream);

    // ---- layer 1: gather -> MLP (bf16 h1 + partial) -> reduce stats1 ----
    gather_k<0><<<gblocks, 256, 0, stream>>>((const u32*)xb, offs, deg, slots,
                                             nullptr, nullptr, nullptr, (u32*)xa, N);
    mlp_mfma_k<<<mblocks, 256, 0, stream>>>(xa, wf1a, b1a, wf1b, b1b,
                                            h1, partial, N);
    reduce_k<<<32, 256, 0, stream>>>(partial, stats1, mblocks);

    // ---- layer 2: gather (BN1 folded) -> MLP (bf16 h2 -> h1 buf) -> stats2 ----
    gather_k<1><<<gblocks, 256, 0, stream>>>((const u32*)h1, offs, deg, slots,
                                             stats1, g1, be1, (u32*)xa, N);
    mlp_mfma_k<<<mblocks, 256, 0, stream>>>(xa, wf2a, b2a, wf2b, b2b,
                                            h1, partial, N);
    reduce_k<<<32, 256, 0, stream>>>(partial, stats2, mblocks);

    // ---- final BN: bf16 h2 -> f32 d_out ----
    bn_apply_bf_k<<<2048, 256, 0, stream>>>((const u32*)h1, stats2, g2, be2, h, N);
}

// Round 12
// 275.431 us; speedup vs baseline: 1.1287x; 1.0235x over previous
//
#include <hip/hip_runtime.h>
#include <hip/hip_bf16.h>

typedef unsigned int u32;
typedef unsigned short u16;
typedef short bf16x8 __attribute__((ext_vector_type(8)));
typedef float f32x4 __attribute__((ext_vector_type(4)));

static __device__ __forceinline__ float bf_lo(u32 v) { return __uint_as_float(v << 16); }
static __device__ __forceinline__ float bf_hi(u32 v) { return __uint_as_float(v & 0xffff0000u); }
static __device__ __forceinline__ u16 f2bf(float f) {
    u32 u = __float_as_uint(f);
    u32 r = u + 0x7fffu + ((u >> 16) & 1u);   // RNE; inputs finite
    return (u16)(r >> 16);
}
static __device__ __forceinline__ u32 pack2(float a, float b) {
    return ((u32)f2bf(b) << 16) | (u32)f2bf(a);
}

// ---------------------------------------------------------------------------
// merged prep: blocks [0,2048) convert f32->bf16; [2048,2304) bhist;
// [2304,2560) wprep (4 weight mats -> fragment-ordered bf16)
// ---------------------------------------------------------------------------
__global__ __launch_bounds__(256) void prep_k(const float* __restrict__ x,
                                              u32* __restrict__ out2, int total4,
                                              const int* __restrict__ edst,
                                              int* __restrict__ gcount, int E, int NB,
                                              const float* __restrict__ Wa,
                                              const float* __restrict__ Wb,
                                              const float* __restrict__ Wc,
                                              const float* __restrict__ Wd,
                                              u16* __restrict__ Wf)
{
    int b = blockIdx.x, t = threadIdx.x;
    if (b < 2048) {                       // ---- convert role ----
        for (int i = b * 256 + t; i < total4; i += 2048 * 256) {
            float4 v = reinterpret_cast<const float4*>(x)[i];
            out2[2 * i + 0] = pack2(v.x, v.y);
            out2[2 * i + 1] = pack2(v.z, v.w);
        }
    } else if (b < 2304) {                // ---- bhist role ----
        __shared__ int lh[1024];
        for (int i = t; i < 1024; i += 256) lh[i] = 0;
        __syncthreads();
        for (int e = (b - 2048) * 256 + t; e < E; e += 256 * 256)
            atomicAdd(&lh[edst[e] >> 7], 1);
        __syncthreads();
        for (int bb = t; bb < NB; bb += 256)
            if (lh[bb]) atomicAdd(&gcount[bb], lh[bb]);
    } else {                              // ---- wprep role ----
        int g = (b - 2304) * 256 + t;     // 0..65535
        int which = g >> 14;
        int tt = g & 16383;
        const float* W = which == 0 ? Wa : which == 1 ? Wb : which == 2 ? Wc : Wd;
        int j  = tt & 7;
        int l  = (tt >> 3) & 63;
        int nb = (tt >> 9) & 7;
        int kg = (tt >> 12) & 3;
        int k  = kg * 32 + (l >> 4) * 8 + j;
        int n  = nb * 16 + (l & 15);
        Wf[g] = f2bf(W[k * 128 + n]);
    }
}

__global__ __launch_bounds__(1024) void bscan_k(const int* __restrict__ gcount,
                                                int* __restrict__ goffs,
                                                int* __restrict__ gcur, int NB)
{
    __shared__ int s[1024];
    int t = threadIdx.x;
    int v = (t < NB) ? gcount[t] : 0;
    s[t] = v; __syncthreads();
    for (int d = 1; d < 1024; d <<= 1) {
        int x = (t >= d) ? s[t - d] : 0;
        __syncthreads();
        s[t] += x;
        __syncthreads();
    }
    if (t < NB) { int o = s[t] - v; goffs[t] = o; gcur[t] = o; }
    if (t == NB - 1) goffs[NB] = s[t];
}

__global__ __launch_bounds__(256) void bfill_k(const int* __restrict__ esrc,
                                               const int* __restrict__ edst,
                                               int* __restrict__ gcur,
                                               u32* __restrict__ bpacked, int E, int NB)
{
    __shared__ int lh[1024];
    __shared__ int lbase[1024];
    int t = threadIdx.x;
    for (int i = t; i < 1024; i += 256) lh[i] = 0;
    __syncthreads();
    int per = (E + gridDim.x - 1) / gridDim.x;
    int lo = blockIdx.x * per;
    int hi = lo + per; if (hi > E) hi = E;
    for (int e = lo + t; e < hi; e += 256) atomicAdd(&lh[edst[e] >> 7], 1);
    __syncthreads();
    for (int b = t; b < NB; b += 256) {
        int c = lh[b];
        lbase[b] = c ? atomicAdd(&gcur[b], c) : 0;
    }
    __syncthreads();
    for (int i = t; i < 1024; i += 256) lh[i] = 0;   // reuse as local cursor
    __syncthreads();
    for (int e = lo + t; e < hi; e += 256) {
        int d = edst[e];
        int b = d >> 7;
        int idx = atomicAdd(&lh[b], 1);
        bpacked[lbase[b] + idx] = ((u32)(d & 127) << 17) | (u32)esrc[e];
    }
}

// ---------------------------------------------------------------------------
// fine counting sort within each bucket -> dst-sorted slots + per-row offs/deg
// ---------------------------------------------------------------------------
__global__ __launch_bounds__(256) void fsort_k(const u32* __restrict__ bpacked,
                                               const int* __restrict__ goffs,
                                               int* __restrict__ slots,
                                               int* __restrict__ offs,
                                               int* __restrict__ deg, int N)
{
    __shared__ int cnt[128];
    __shared__ int roff[128];
    __shared__ int sb[128];
    int b = blockIdx.x, t = threadIdx.x;
    int start = goffs[b], end = goffs[b + 1];
    if (t < 128) cnt[t] = 0;
    __syncthreads();
    for (int e = start + t; e < end; e += 256)
        atomicAdd(&cnt[bpacked[e] >> 17], 1);
    __syncthreads();
    if (t < 128) sb[t] = cnt[t];
    __syncthreads();
    for (int d = 1; d < 128; d <<= 1) {
        int x = (t < 128 && t >= d) ? sb[t - d] : 0;
        __syncthreads();
        if (t < 128) sb[t] += x;
        __syncthreads();
    }
    if (t < 128) roff[t] = sb[t] - cnt[t];   // exclusive prefix
    __syncthreads();
    int row0 = b * 128;
    if (t < 128 && row0 + t < N) {
        offs[row0 + t] = start + roff[t];
        deg[row0 + t]  = cnt[t];
    }
    if (t < 128) cnt[t] = 0;   // reuse as cursor
    __syncthreads();
    for (int e = start + t; e < end; e += 256) {
        u32 pk = bpacked[e];
        int local = (int)(pk >> 17);
        int idx = atomicAdd(&cnt[local], 1);
        slots[start + roff[local] + idx] = (int)(pk & 0x1FFFF);
    }
}

// ---------------------------------------------------------------------------
// gather-aggregate: one wave per row, scalar-hoisted CSR state (round 11),
// PLUS single-round-trip tail: up to 15 scalar-guarded loads into zeroed
// regs, then unconditional accumulate (bf(0)=0) -> no serial 8/4/1 ladder.
// MODE 0: xa[row] = bf16( x[row] + sum_nbr x[s] )
// MODE 1: prev-layer BN folded in: xa[row] = bf16( sc.(h+sum) + (deg+1).sh )
// ---------------------------------------------------------------------------
#define ROWP(s) reinterpret_cast<const u32*>(xbase + ((size_t)(u32)(s) << 8))

template<int MODE>
__global__ __launch_bounds__(256) void gather_k(const u32* __restrict__ xb2,
                                                const int* __restrict__ offs,
                                                const int* __restrict__ deg,
                                                const int* __restrict__ slots,
                                                const float* __restrict__ stats_in,
                                                const float* __restrict__ g_in,
                                                const float* __restrict__ be_in,
                                                u32* __restrict__ xa2, int N)
{
    __shared__ float sc[128], sh[128];
    int t = threadIdx.x;
    if (MODE == 1) {
        if (t < 128) {
            float invN = 1.0f / (float)N;
            float mean = stats_in[t] * invN;
            float var  = stats_in[128 + t] * invN - mean * mean;
            float s = g_in[t] * rsqrtf(var + 1e-5f);
            sc[t] = s;
            sh[t] = be_in[t] - mean * s;
        }
        __syncthreads();
    }

    int row = blockIdx.x * 4 + (t >> 6);
    if (row >= N) return;
    int lane = t & 63;
    const char* xbase = (const char*)xb2;

    u32 self = ROWP(row)[lane];
    float ax0 = bf_lo(self), ay0 = bf_hi(self);
    float ax1 = 0.f, ay1 = 0.f, ax2 = 0.f, ay2 = 0.f, ax3 = 0.f, ay3 = 0.f;

    // wave-uniform CSR state -> SGPRs
    int ustart = __builtin_amdgcn_readfirstlane(offs[row]);
    int udg    = __builtin_amdgcn_readfirstlane(deg[row]);

    int e = 0;
    for (; e + 16 <= udg; e += 16) {   // scalar slot fetch, 16 loads in flight
        int s0 = slots[ustart + e + 0],  s1 = slots[ustart + e + 1];
        int s2 = slots[ustart + e + 2],  s3 = slots[ustart + e + 3];
        int s4 = slots[ustart + e + 4],  s5 = slots[ustart + e + 5];
        int s6 = slots[ustart + e + 6],  s7 = slots[ustart + e + 7];
        int s8 = slots[ustart + e + 8],  s9 = slots[ustart + e + 9];
        int sA = slots[ustart + e + 10], sB = slots[ustart + e + 11];
        int sC = slots[ustart + e + 12], sD = slots[ustart + e + 13];
        int sE = slots[ustart + e + 14], sF = slots[ustart + e + 15];
        u32 v0 = ROWP(s0)[lane], v1 = ROWP(s1)[lane];
        u32 v2 = ROWP(s2)[lane], v3 = ROWP(s3)[lane];
        u32 v4 = ROWP(s4)[lane], v5 = ROWP(s5)[lane];
        u32 v6 = ROWP(s6)[lane], v7 = ROWP(s7)[lane];
        u32 v8 = ROWP(s8)[lane], v9 = ROWP(s9)[lane];
        u32 vA = ROWP(sA)[lane], vB = ROWP(sB)[lane];
        u32 vC = ROWP(sC)[lane], vD = ROWP(sD)[lane];
        u32 vE = ROWP(sE)[lane], vF = ROWP(sF)[lane];
        ax0 += bf_lo(v0); ay0 += bf_hi(v0);  ax1 += bf_lo(v1); ay1 += bf_hi(v1);
        ax2 += bf_lo(v2); ay2 += bf_hi(v2);  ax3 += bf_lo(v3); ay3 += bf_hi(v3);
        ax0 += bf_lo(v4); ay0 += bf_hi(v4);  ax1 += bf_lo(v5); ay1 += bf_hi(v5);
        ax2 += bf_lo(v6); ay2 += bf_hi(v6);  ax3 += bf_lo(v7); ay3 += bf_hi(v7);
        ax0 += bf_lo(v8); ay0 += bf_hi(v8);  ax1 += bf_lo(v9); ay1 += bf_hi(v9);
        ax2 += bf_lo(vA); ay2 += bf_hi(vA);  ax3 += bf_lo(vB); ay3 += bf_hi(vB);
        ax0 += bf_lo(vC); ay0 += bf_hi(vC);  ax1 += bf_lo(vD); ay1 += bf_hi(vD);
        ax2 += bf_lo(vE); ay2 += bf_hi(vE);  ax3 += bf_lo(vF); ay3 += bf_hi(vF);
    }
    int k = udg - e;                   // 0..15, wave-uniform
    if (k) {
        // slot reads may overrun this row (into next row's slots / 64B pad):
        // values masked below, so harmless. All loads grouped -> 1 round trip.
        int s0 = slots[ustart + e + 0],  s1 = slots[ustart + e + 1];
        int s2 = slots[ustart + e + 2],  s3 = slots[ustart + e + 3];
        int s4 = slots[ustart + e + 4],  s5 = slots[ustart + e + 5];
        int s6 = slots[ustart + e + 6],  s7 = slots[ustart + e + 7];
        int s8 = slots[ustart + e + 8],  s9 = slots[ustart + e + 9];
        int sA = slots[ustart + e + 10], sB = slots[ustart + e + 11];
        int sC = slots[ustart + e + 12], sD = slots[ustart + e + 13];
        int sE = slots[ustart + e + 14];
        u32 v0 = 0, v1 = 0, v2 = 0, v3 = 0, v4 = 0, v5 = 0, v6 = 0, v7 = 0;
        u32 v8 = 0, v9 = 0, vA = 0, vB = 0, vC = 0, vD = 0, vE = 0;
        v0 = ROWP(s0)[lane];                       // k >= 1
        if (k > 1)  v1 = ROWP(s1)[lane];
        if (k > 2)  v2 = ROWP(s2)[lane];
        if (k > 3)  v3 = ROWP(s3)[lane];
        if (k > 4)  v4 = ROWP(s4)[lane];
        if (k > 5)  v5 = ROWP(s5)[lane];
        if (k > 6)  v6 = ROWP(s6)[lane];
        if (k > 7)  v7 = ROWP(s7)[lane];
        if (k > 8)  v8 = ROWP(s8)[lane];
        if (k > 9)  v9 = ROWP(s9)[lane];
        if (k > 10) vA = ROWP(sA)[lane];
        if (k > 11) vB = ROWP(sB)[lane];
        if (k > 12) vC = ROWP(sC)[lane];
        if (k > 13) vD = ROWP(sD)[lane];
        if (k > 14) vE = ROWP(sE)[lane];
        // bf(0) == 0.0f -> unconditional accumulate
        ax0 += bf_lo(v0); ay0 += bf_hi(v0);  ax1 += bf_lo(v1); ay1 += bf_hi(v1);
        ax2 += bf_lo(v2); ay2 += bf_hi(v2);  ax3 += bf_lo(v3); ay3 += bf_hi(v3);
        ax0 += bf_lo(v4); ay0 += bf_hi(v4);  ax1 += bf_lo(v5); ay1 += bf_hi(v5);
        ax2 += bf_lo(v6); ay2 += bf_hi(v6);  ax3 += bf_lo(v7); ay3 += bf_hi(v7);
        ax0 += bf_lo(v8); ay0 += bf_hi(v8);  ax1 += bf_lo(v9); ay1 += bf_hi(v9);
        ax2 += bf_lo(vA); ay2 += bf_hi(vA);  ax3 += bf_lo(vB); ay3 += bf_hi(vB);
        ax0 += bf_lo(vC); ay0 += bf_hi(vC);  ax1 += bf_lo(vD); ay1 += bf_hi(vD);
        ax2 += bf_lo(vE); ay2 += bf_hi(vE);
    }

    float ax = (ax0 + ax1) + (ax2 + ax3);
    float ay = (ay0 + ay1) + (ay2 + ay3);
    if (MODE == 1) {
        float d1 = (float)(udg + 1);
        ax = sc[2 * lane]     * ax + d1 * sh[2 * lane];
        ay = sc[2 * lane + 1] * ay + d1 * sh[2 * lane + 1];
    }
    xa2[(size_t)row * 64 + lane] = pack2(ax, ay);
}

// ---------------------------------------------------------------------------
// fused MFMA MLP: h = relu(relu(XA@Wa + ba)@Wb + bb) -> bf16 out + partials.
// W2 fragment loads issued BEFORE the relu->ta write phase (independent of
// ta) so their global latency hides under the LDS writes.
// ---------------------------------------------------------------------------
__global__ __launch_bounds__(256) void mlp_mfma_k(
    const u16* __restrict__ xa,
    const u16* __restrict__ wfa, const float* __restrict__ ba,
    const u16* __restrict__ wfb, const float* __restrict__ bb,
    u16* __restrict__ hb_out, float* __restrict__ partial, int N)
{
    __shared__ short ta[64 * 128];   // 16 KB tile (bf16, swizzled), reused
    __shared__ float ssum[256];

    int t = threadIdx.x;
    int w = t >> 6, l = t & 63;
    int row0 = blockIdx.x * 64;

    // stage XA tile (swizzled)
    for (int c = t; c < 1024; c += 256) {
        int r = c >> 4, ci = c & 15;
        int dst = (r * 128 + ci * 8) ^ ((r & 7) << 3);
        f32x4 v;
        if (row0 + r < N)
            v = *reinterpret_cast<const f32x4*>(xa + ((size_t)(row0 + r) * 128 + ci * 8));
        else
            v = f32x4{0.f, 0.f, 0.f, 0.f};
        *reinterpret_cast<f32x4*>(ta + dst) = v;
    }

    // W1 fragments
    bf16x8 wf[2][4];
#pragma unroll
    for (int nr = 0; nr < 2; ++nr) {
        int nb = 2 * w + nr;
#pragma unroll
        for (int kg = 0; kg < 4; ++kg)
            wf[nr][kg] = *reinterpret_cast<const bf16x8*>(
                wfa + ((size_t)((kg * 8 + nb) * 64 + l)) * 8);
    }
    __syncthreads();

    int rr = l & 15;
    int kg8 = l >> 4;

    f32x4 acc[4][2];
#pragma unroll
    for (int mr = 0; mr < 4; ++mr)
#pragma unroll
        for (int nr = 0; nr < 2; ++nr)
            acc[mr][nr] = f32x4{0.f, 0.f, 0.f, 0.f};

#pragma unroll
    for (int mr = 0; mr < 4; ++mr) {
        int r = mr * 16 + rr;
        bf16x8 af[4];
#pragma unroll
        for (int kg = 0; kg < 4; ++kg) {
            int idx = (r * 128 + kg * 32 + kg8 * 8) ^ ((r & 7) << 3);
            af[kg] = *reinterpret_cast<const bf16x8*>(ta + idx);
        }
#pragma unroll
        for (int nr = 0; nr < 2; ++nr)
#pragma unroll
            for (int kg = 0; kg < 4; ++kg)
                acc[mr][nr] = __builtin_amdgcn_mfma_f32_16x16x32_bf16(
                    af[kg], wf[nr][kg], acc[mr][nr], 0, 0, 0);
    }
    __syncthreads();   // all GEMM1 reads of ta complete

    // W2 fragments (independent of ta -> issue before the relu-write phase)
    bf16x8 wf2[2][4];
#pragma unroll
    for (int nr = 0; nr < 2; ++nr) {
        int nb = 2 * w + nr;
#pragma unroll
        for (int kg = 0; kg < 4; ++kg)
            wf2[nr][kg] = *reinterpret_cast<const bf16x8*>(
                wfb + ((size_t)((kg * 8 + nb) * 64 + l)) * 8);
    }

    // bias + relu -> back into ta
    int colb = w * 32;
    float b0 = ba[colb + rr];
    float b1 = ba[colb + 16 + rr];
#pragma unroll
    for (int mr = 0; mr < 4; ++mr)
#pragma unroll
        for (int nr = 0; nr < 2; ++nr) {
            float bb_ = nr ? b1 : b0;
            int col = colb + nr * 16 + rr;
#pragma unroll
            for (int reg = 0; reg < 4; ++reg) {
                int row = mr * 16 + kg8 * 4 + reg;
                float v = fmaxf(acc[mr][nr][reg] + bb_, 0.0f);
                ta[(row * 128 + col) ^ ((row & 7) << 3)] = (short)f2bf(v);
            }
        }
    __syncthreads();

#pragma unroll
    for (int mr = 0; mr < 4; ++mr)
#pragma unroll
        for (int nr = 0; nr < 2; ++nr)
            acc[mr][nr] = f32x4{0.f, 0.f, 0.f, 0.f};

#pragma unroll
    for (int mr = 0; mr < 4; ++mr) {
        int r = mr * 16 + rr;
        bf16x8 af[4];
#pragma unroll
        for (int kg = 0; kg < 4; ++kg) {
            int idx = (r * 128 + kg * 32 + kg8 * 8) ^ ((r & 7) << 3);
            af[kg] = *reinterpret_cast<const bf16x8*>(ta + idx);
        }
#pragma unroll
        for (int nr = 0; nr < 2; ++nr)
#pragma unroll
            for (int kg = 0; kg < 4; ++kg)
                acc[mr][nr] = __builtin_amdgcn_mfma_f32_16x16x32_bf16(
                    af[kg], wf2[nr][kg], acc[mr][nr], 0, 0, 0);
    }

    // bias + relu + bf16 store + per-block BN stat partial
    float c0 = bb[colb + rr];
    float c1 = bb[colb + 16 + rr];
    float s0 = 0.f, q0 = 0.f, s1 = 0.f, q1 = 0.f;
#pragma unroll
    for (int mr = 0; mr < 4; ++mr) {
#pragma unroll
        for (int reg = 0; reg < 4; ++reg) {
            int row = row0 + mr * 16 + kg8 * 4 + reg;
            bool ok = row < N;
            float v0 = fmaxf(acc[mr][0][reg] + c0, 0.0f);
            float v1 = fmaxf(acc[mr][1][reg] + c1, 0.0f);
            if (ok) {
                hb_out[(size_t)row * 128 + colb + rr]      = f2bf(v0);
                hb_out[(size_t)row * 128 + colb + 16 + rr] = f2bf(v1);
                s0 += v0; q0 += v0 * v0;
                s1 += v1; q1 += v1 * v1;
            }
        }
    }
    s0 += __shfl_xor(s0, 16); s0 += __shfl_xor(s0, 32);
    q0 += __shfl_xor(q0, 16); q0 += __shfl_xor(q0, 32);
    s1 += __shfl_xor(s1, 16); s1 += __shfl_xor(s1, 32);
    q1 += __shfl_xor(q1, 16); q1 += __shfl_xor(q1, 32);
    if (kg8 == 0) {
        ssum[colb + rr]            = s0;
        ssum[128 + colb + rr]      = q0;
        ssum[colb + 16 + rr]       = s1;
        ssum[128 + colb + 16 + rr] = q1;
    }
    __syncthreads();
    partial[(size_t)blockIdx.x * 256 + t] = ssum[t];   // coalesced, no atomics
}

// ---------------------------------------------------------------------------
// reduce partials (nrows x 256) -> stats[256]
// ---------------------------------------------------------------------------
__global__ __launch_bounds__(256) void reduce_k(const float* __restrict__ partial,
                                                float* __restrict__ stats, int nrows)
{
    int t = threadIdx.x;
    int chunk = (nrows + gridDim.x - 1) / gridDim.x;
    int lo = blockIdx.x * chunk;
    int hi = lo + chunk; if (hi > nrows) hi = nrows;
    float acc = 0.f;
    for (int r = lo; r < hi; ++r)
        acc += partial[(size_t)r * 256 + t];
    if (hi > lo) atomicAdd(&stats[t], acc);
}

// ---------------------------------------------------------------------------
// final BN: read bf16 h2, write f32 d_out (single d_out write pass)
// ---------------------------------------------------------------------------
__global__ __launch_bounds__(256) void bn_apply_bf_k(
    const u32* __restrict__ h2b, const float* __restrict__ stats,
    const float* __restrict__ gamma, const float* __restrict__ beta,
    float* __restrict__ out, int N)
{
    __shared__ float sc[128], sh[128];
    int t = threadIdx.x;
    if (t < 128) {
        float invN = 1.0f / (float)N;
        float mean = stats[t] * invN;
        float var  = stats[128 + t] * invN - mean * mean;
        float s = gamma[t] * rsqrtf(var + 1e-5f);
        sc[t] = s;
        sh[t] = beta[t] - mean * s;
    }
    __syncthreads();
    int total2 = N * 64;   // u32 count
    for (int i = blockIdx.x * 256 + t; i < total2; i += gridDim.x * 256) {
        u32 v = h2b[i];
        int c = (i & 63) * 2;
        float2 o;
        o.x = bf_lo(v) * sc[c]     + sh[c];
        o.y = bf_hi(v) * sc[c + 1] + sh[c + 1];
        reinterpret_cast<float2*>(out)[i] = o;
    }
}

// ---------------------------------------------------------------------------
extern "C" void kernel_launch(void* const* d_in, const int* in_sizes, int n_in,
                              void* d_out, int out_size, void* d_ws, size_t ws_size,
                              hipStream_t stream)
{
    const float* x   = (const float*)d_in[0];
    const int*   ei  = (const int*)d_in[1];
    const float* W1a = (const float*)d_in[2];
    const float* b1a = (const float*)d_in[3];
    const float* W1b = (const float*)d_in[4];
    const float* b1b = (const float*)d_in[5];
    const float* g1  = (const float*)d_in[6];
    const float* be1 = (const float*)d_in[7];
    const float* W2a = (const float*)d_in[8];
    const float* b2a = (const float*)d_in[9];
    const float* W2b = (const float*)d_in[10];
    const float* b2b = (const float*)d_in[11];
    const float* g2  = (const float*)d_in[12];
    const float* be2 = (const float*)d_in[13];

    const int N = in_sizes[0] / 128;
    const int E = in_sizes[1] / 2;
    const int* esrc = ei;
    const int* edst = ei + E;
    const int NB = (N + 127) >> 7;   // 128-row buckets; requires N <= 131072

    const int mblocks = (N + 63) / 64;
    const int gblocks = (N + 3) / 4;   // 1 row/wave, 4 rows/block

    // ---- workspace carve ----
    char* p = (char*)d_ws;
    const size_t featb = (size_t)N * 128 * sizeof(u16);     // 25.6 MB
    u16* xa = (u16*)p;            p += featb;               // gather output
    u16* h1 = (u16*)p;            p += featb;               // layer-1/2 bf16 output
    u16* xb = (u16*)p;            p += featb;               // bf16 input features
    u16* wf = (u16*)p;            p += 4 * 16384 * sizeof(u16);
    int* slots = (int*)p;         p += (size_t)E * sizeof(int) + 64;  // +64B tail overread pad
    int* deg   = (int*)p;         p += (size_t)N * sizeof(int);
    int* offs  = (int*)p;         p += (size_t)N * sizeof(int);
    int* gcount = (int*)p;        p += 1024 * sizeof(int);
    int* goffs  = (int*)p;        p += 1032 * sizeof(int);
    int* gcur   = (int*)p;        p += 1024 * sizeof(int);
    float* stats = (float*)p;     p += 512 * sizeof(float);
    float* partial = (float*)p;   p += (size_t)mblocks * 256 * sizeof(float);
    u32* bpacked = (u32*)xa;      // alias (E*4 = 6.4MB <= featb), dead early

    u16* wf1a = wf;
    u16* wf1b = wf + 16384;
    u16* wf2a = wf + 32768;
    u16* wf2b = wf + 49152;
    float* stats1 = stats;
    float* stats2 = stats + 256;

    float* h = (float*)d_out;

    // ---- one-time prep: merged convert/bhist/wprep -> scan -> fill -> sort --
    hipMemsetAsync(gcount, 0, 1024 * sizeof(int), stream);
    prep_k<<<2560, 256, 0, stream>>>(x, (u32*)xb, N * 32,
                                     edst, gcount, E, NB,
                                     W1a, W1b, W2a, W2b, wf);
    bscan_k<<<1, 1024, 0, stream>>>(gcount, goffs, gcur, NB);
    bfill_k<<<256, 256, 0, stream>>>(esrc, edst, gcur, bpacked, E, NB);
    fsort_k<<<NB, 256, 0, stream>>>(bpacked, goffs, slots, offs, deg, N);
    hipMemsetAsync(stats, 0, 512 * sizeof(float), stream);

    // ---- layer 1: gather -> MLP (bf16 h1 + partial) -> reduce stats1 ----
    gather_k<0><<<gblocks, 256, 0, stream>>>((const u32*)xb, offs, deg, slots,
                                             nullptr, nullptr, nullptr, (u32*)xa, N);
    mlp_mfma_k<<<mblocks, 256, 0, stream>>>(xa, wf1a, b1a, wf1b, b1b,
                                            h1, partial, N);
    reduce_k<<<32, 256, 0, stream>>>(partial, stats1, mblocks);

    // ---- layer 2: gather (BN1 folded) -> MLP (bf16 h2 -> h1 buf) -> stats2 ----
    gather_k<1><<<gblocks, 256, 0, stream>>>((const u32*)h1, offs, deg, slots,
                                             stats1, g1, be1, (u32*)xa, N);
    mlp_mfma_k<<<mblocks, 256, 0, stream>>>(xa, wf2a, b2a, wf2b, b2b,
                                            h1, partial, N);
    reduce_k<<<32, 256, 0, stream>>>(partial, stats2, mblocks);

    // ---- final BN: bf16 h2 -> f32 d_out ----
    bn_apply_bf_k<<<2048, 256, 0, stream>>>((const u32*)h1, stats2, g2, be2, h, N);
}